// Round 4
// baseline (484.622 us; speedup 1.0000x reference)
//
#include <hip/hip_runtime.h>

typedef __attribute__((ext_vector_type(8))) short bf16x8;
typedef __attribute__((ext_vector_type(4))) float f32x4;

#define HIDDEN 2880
#define QKV_DIM 5120
#define NH 64
#define NKV 8
#define HD 64
#define ATT_DIM 4096
#define WINDOW 128
#define SM_SCALE 0.125f

__device__ __forceinline__ ushort f2bf(float f) {
  union { float f; unsigned u; } a; a.f = f;
  unsigned r = a.u + 0x7fffu + ((a.u >> 16) & 1u);
  return (ushort)(r >> 16);
}

__device__ __forceinline__ void gload_lds16(const void* g, void* l) {
  __builtin_amdgcn_global_load_lds((const __attribute__((address_space(1))) void*)g,
                                   (__attribute__((address_space(3))) void*)l, 16, 0, 0);
}

// ---------------- f32 -> bf16 convert ----------------
__global__ __launch_bounds__(256) void cvt_f32_bf16(const float* __restrict__ in,
                                                    ushort* __restrict__ out, int n4) {
  int i = blockIdx.x * blockDim.x + threadIdx.x;
  int stride = gridDim.x * blockDim.x;
  for (; i < n4; i += stride) {
    float4 v = ((const float4*)in)[i];
    ushort4 o = { f2bf(v.x), f2bf(v.y), f2bf(v.z), f2bf(v.w) };
    ((ushort4*)out)[i] = o;
  }
}

// ---------------- RMSNorm -> bf16 ----------------
__global__ __launch_bounds__(256) void rmsnorm_bf16(const float* __restrict__ x,
                                                    const float* __restrict__ scale,
                                                    ushort* __restrict__ t) {
  int row = blockIdx.x;
  int tid = threadIdx.x;
  const float4* xr = (const float4*)(x + (size_t)row * HIDDEN);
  float4 a0 = xr[tid];
  float4 a1 = xr[tid + 256];
  bool has2 = tid < 208;
  float4 a2 = has2 ? xr[tid + 512] : float4{0.f, 0.f, 0.f, 0.f};
  float ss = a0.x*a0.x + a0.y*a0.y + a0.z*a0.z + a0.w*a0.w
           + a1.x*a1.x + a1.y*a1.y + a1.z*a1.z + a1.w*a1.w
           + a2.x*a2.x + a2.y*a2.y + a2.z*a2.z + a2.w*a2.w;
  for (int m = 1; m < 64; m <<= 1) ss += __shfl_xor(ss, m, 64);
  __shared__ float red[4];
  if ((tid & 63) == 0) red[tid >> 6] = ss;
  __syncthreads();
  ss = red[0] + red[1] + red[2] + red[3];
  float r = rsqrtf(ss / (float)HIDDEN + 1e-5f);
  ushort4* tr = (ushort4*)(t + (size_t)row * HIDDEN);
  const float4* sc4 = (const float4*)scale;
  {
    float4 s = sc4[tid];
    ushort4 o = { f2bf(a0.x*r*s.x), f2bf(a0.y*r*s.y), f2bf(a0.z*r*s.z), f2bf(a0.w*r*s.w) };
    tr[tid] = o;
  }
  {
    float4 s = sc4[tid + 256];
    ushort4 o = { f2bf(a1.x*r*s.x), f2bf(a1.y*r*s.y), f2bf(a1.z*r*s.z), f2bf(a1.w*r*s.w) };
    tr[tid + 256] = o;
  }
  if (has2) {
    float4 s = sc4[tid + 512];
    ushort4 o = { f2bf(a2.x*r*s.x), f2bf(a2.y*r*s.y), f2bf(a2.z*r*s.z), f2bf(a2.w*r*s.w) };
    tr[tid + 512] = o;
  }
}

// ---------------- register-direct bf16 GEMM: C[M,N] = A[M,K] * B[N,K]^T + bias (+resid) ----
// No LDS, no barriers. Block = 4 waves (2x2), wave tile 64x64, block tile 128x128.
// MFMA fragments load DIRECTLY from global: lane pattern {r, r+16, r+32, r+48} reads one
// contiguous 64B line per 16 rows -> perfectly coalesced; A/B panels are L2-resident
// (small-M regime: total L2 frag traffic ~530 MB @ 36 TB/s ~ 15 us chip-wide).
// Latency hidden by 16 independent loads/K-tile (vmcnt pipelining) + ~7 waves/CU.
template <int EPI>
__global__ __launch_bounds__(256)
void gemm_reg(const ushort* __restrict__ A, const ushort* __restrict__ B,
              const float* __restrict__ bias, const float* __restrict__ resid,
              float* __restrict__ C, int M, int N, int K, int NM) {
  const int tid = threadIdx.x;
  const int wave = tid >> 6, lane = tid & 63;
  // bijective XCD swizzle (m204); bid is bm-fastest so same-XCD chunk shares bn panel
  int nwg = gridDim.x, orig = blockIdx.x;
  int q = nwg >> 3, r8 = nwg & 7, xcd = orig & 7, seq = orig >> 3;
  int swz = (xcd < r8 ? xcd * (q + 1) : r8 * (q + 1) + (xcd - r8) * q) + seq;
  int bm = swz % NM, bn = swz / NM;
  const int row0 = bm * 128 + (wave >> 1) * 64;
  const int col0 = bn * 128 + (wave & 1) * 64;
  const int l15 = lane & 15, hi = lane >> 4;

  // per-lane 32-bit byte row offsets (row * K * 2 < 2^31 for all our shapes)
  unsigned arow[4], brow[4];
#pragma unroll
  for (int i = 0; i < 4; ++i) {
    arow[i] = (unsigned)(row0 + i * 16 + l15) * (unsigned)(K * 2);
    int bcol = col0 + i * 16 + l15;
    if (bcol > N - 1) bcol = N - 1;  // masked-N clamp (out GEMM); garbage cols never written
    brow[i] = (unsigned)bcol * (unsigned)(K * 2);
  }
  const unsigned kpart = (unsigned)(hi * 16);  // byte offset of this lane's k-chunk
  const char* Ab = (const char*)A;
  const char* Bb = (const char*)B;

  f32x4 acc[4][4] = {};

#pragma unroll 2
  for (int k0 = 0; k0 < K; k0 += 64) {
    const unsigned kb = (unsigned)(k0 * 2) + kpart;
    bf16x8 af[4][2], bfr[4][2];
#pragma unroll
    for (int ks = 0; ks < 2; ++ks)
#pragma unroll
      for (int i = 0; i < 4; ++i) {
        af[i][ks]  = *(const bf16x8*)(Ab + (size_t)(arow[i] + kb + ks * 64));
        bfr[i][ks] = *(const bf16x8*)(Bb + (size_t)(brow[i] + kb + ks * 64));
      }
#pragma unroll
    for (int ks = 0; ks < 2; ++ks)
#pragma unroll
      for (int nt = 0; nt < 4; ++nt)
#pragma unroll
        for (int mt = 0; mt < 4; ++mt)
          acc[mt][nt] = __builtin_amdgcn_mfma_f32_16x16x32_bf16(af[mt][ks], bfr[nt][ks], acc[mt][nt], 0, 0, 0);
  }

  // epilogue: C/D layout col=lane&15, row=(lane>>4)*4+r (m89-verified)
#pragma unroll
  for (int mt = 0; mt < 4; ++mt) {
#pragma unroll
    for (int nt = 0; nt < 4; ++nt) {
#pragma unroll
      for (int rr = 0; rr < 4; ++rr) {
        int row = row0 + mt * 16 + (hi << 2) + rr;
        int col = col0 + nt * 16 + l15;
        if (col < N) {
          float v = acc[mt][nt][rr] + bias[col];
          if (EPI == 1) v += resid[(size_t)row * N + col];
          C[(size_t)row * N + col] = v;
        }
      }
    }
  }
}

// ---------------- RoPE + split + bf16 cast ----------------
__global__ __launch_bounds__(256)
void rope_split(const float* __restrict__ qkv, ushort* __restrict__ qb,
                ushort* __restrict__ kb, ushort* __restrict__ vb) {
  int tok = blockIdx.x;
  int tid = threadIdx.x;
  __shared__ float cs[32], sn[32];
  if (tid < 32) {
    float d = (float)tid;
    float freq = powf(150000.0f, d / 32.0f);
    float conc = 0.1f * logf(32.0f) + 1.0f;
    float lg = logf(150000.0f);
    float low = 32.0f * logf(4096.0f / (32.0f * 6.2831853f)) / lg;
    float high = 32.0f * logf(4096.0f / 6.2831853f) / lg;
    float ramp = (d - low) / (high - low);
    float cl = fminf(fmaxf(ramp, 0.0f), 1.0f);
    float mask = 1.0f - cl;
    float inv_freq = (1.0f - mask) / (32.0f * freq) + mask / freq;
    float fr = (float)tok * inv_freq;
    cs[tid] = cosf(fr) * conc;
    sn[tid] = sinf(fr) * conc;
  }
  __syncthreads();
  const float* row = qkv + (size_t)tok * QKV_DIM;
#pragma unroll
  for (int it = 0; it < 8; ++it) {
    int p = tid + it * 256;
    int hd = p >> 5, d = p & 31;
    float x1 = row[hd * 64 + d], x2 = row[hd * 64 + d + 32];
    float c = cs[d], s = sn[d];
    size_t o = ((size_t)tok * NH + hd) * HD + d;
    qb[o] = f2bf(x1 * c - x2 * s);
    qb[o + 32] = f2bf(x2 * c + x1 * s);
  }
  {
    int p = tid;
    int hd = p >> 5, d = p & 31;
    float x1 = row[4096 + hd * 64 + d], x2 = row[4096 + hd * 64 + d + 32];
    float c = cs[d], s = sn[d];
    size_t o = ((size_t)tok * NKV + hd) * HD + d;
    kb[o] = f2bf(x1 * c - x2 * s);
    kb[o + 32] = f2bf(x2 * c + x1 * s);
  }
#pragma unroll
  for (int it = 0; it < 2; ++it) {
    int p = tid + it * 256;
    vb[(size_t)tok * (NKV * HD) + p] = f2bf(row[4608 + p]);
  }
}

// ---------------- attention: sliding window 128 + sink ----------------
__global__ __launch_bounds__(512)
void attn_fused(const ushort* __restrict__ qb, const ushort* __restrict__ kb,
                const ushort* __restrict__ vb, const float* __restrict__ sinks,
                ushort* __restrict__ attn, int n) {
  __shared__ __align__(16) ushort Kl[160 * 64];
  __shared__ __align__(16) ushort Vt[64 * 168];
  __shared__ __align__(16) ushort Pl[8][32 * 40];
  int tid = threadIdx.x;
  int wave = tid >> 6, lane = tid & 63;
  int qstart = blockIdx.x * 32;
  int kv = blockIdx.y;
  int head = kv * 8 + wave;
  int key0 = qstart - 128;

  for (int i = 0; i < 3; ++i) {
    int rowb = i * 64 + wave * 8;
    if (rowb < 160) {
      int r = rowb + (lane >> 3);
      int gj = key0 + r; if (gj < 0) gj = 0;
      int chunk = (lane & 7) ^ (lane >> 3);
      gload_lds16(kb + ((size_t)gj * NKV + kv) * HD + chunk * 8, Kl + rowb * 64);
    }
  }
  for (int e = tid; e < 160 * 16; e += 512) {
    int j = e >> 4, d4 = (e & 15) << 2;
    int gj = key0 + j; if (gj < 0) gj = 0;
    ushort4 v = *(const ushort4*)(vb + ((size_t)gj * NKV + kv) * HD + d4);
    Vt[(d4 + 0) * 168 + j] = v.x;
    Vt[(d4 + 1) * 168 + j] = v.y;
    Vt[(d4 + 2) * 168 + j] = v.z;
    Vt[(d4 + 3) * 168 + j] = v.w;
  }
  bf16x8 qf[2][2];
#pragma unroll
  for (int mt = 0; mt < 2; ++mt)
#pragma unroll
    for (int ks = 0; ks < 2; ++ks) {
      int r = qstart + mt * 16 + (lane & 15);
      int kk = ks * 32 + ((lane >> 4) << 3);
      qf[mt][ks] = *(const bf16x8*)(qb + ((size_t)r * NH + head) * HD + kk);
    }
  __syncthreads();

  f32x4 s[2][10] = {};
#pragma unroll
  for (int nt = 0; nt < 10; ++nt) {
#pragma unroll
    for (int ks = 0; ks < 2; ++ks) {
      int r = nt * 16 + (lane & 15);
      int off = (r * 128 + (ks * 32 + ((lane >> 4) << 3)) * 2) ^ ((r & 7) << 4);
      bf16x8 kf = *(const bf16x8*)((const char*)Kl + off);
      s[0][nt] = __builtin_amdgcn_mfma_f32_16x16x32_bf16(qf[0][ks], kf, s[0][nt], 0, 0, 0);
      s[1][nt] = __builtin_amdgcn_mfma_f32_16x16x32_bf16(qf[1][ks], kf, s[1][nt], 0, 0, 0);
    }
  }

  float lrow[2][4];
  float snk = sinks[head];
#pragma unroll
  for (int mt = 0; mt < 2; ++mt) {
#pragma unroll
    for (int r = 0; r < 4; ++r) {
      int i = qstart + mt * 16 + ((lane >> 4) << 2) + r;
      float mx = -1e30f;
#pragma unroll
      for (int nt = 0; nt < 10; ++nt) {
        int j = key0 + nt * 16 + (lane & 15);
        bool ok = (j >= 0) && (j <= i) && (j > i - WINDOW);
        float val = ok ? s[mt][nt][r] * SM_SCALE : -1e30f;
        s[mt][nt][r] = val;
        mx = fmaxf(mx, val);
      }
      mx = fmaxf(mx, __shfl_xor(mx, 1, 64));
      mx = fmaxf(mx, __shfl_xor(mx, 2, 64));
      mx = fmaxf(mx, __shfl_xor(mx, 4, 64));
      mx = fmaxf(mx, __shfl_xor(mx, 8, 64));
      mx = fmaxf(mx, snk);
      float sum = 0.f;
#pragma unroll
      for (int nt = 0; nt < 10; ++nt) {
        float p = expf(s[mt][nt][r] - mx);
        s[mt][nt][r] = p;
        sum += p;
      }
      sum += __shfl_xor(sum, 1, 64);
      sum += __shfl_xor(sum, 2, 64);
      sum += __shfl_xor(sum, 4, 64);
      sum += __shfl_xor(sum, 8, 64);
      sum += expf(snk - mx);
      lrow[mt][r] = sum;
    }
  }

  f32x4 o[2][4] = {};
#pragma unroll
  for (int kc = 0; kc < 5; ++kc) {
    __syncthreads();
#pragma unroll
    for (int mt = 0; mt < 2; ++mt)
#pragma unroll
      for (int t2 = 0; t2 < 2; ++t2) {
        int nt = kc * 2 + t2;
#pragma unroll
        for (int r = 0; r < 4; ++r) {
          int prow = mt * 16 + ((lane >> 4) << 2) + r;
          int pcol = t2 * 16 + (lane & 15);
          Pl[wave][prow * 40 + pcol] = f2bf(s[mt][nt][r]);
        }
      }
    __syncthreads();
    bf16x8 pa[2];
#pragma unroll
    for (int mt = 0; mt < 2; ++mt) {
      int r = mt * 16 + (lane & 15);
      pa[mt] = *(const bf16x8*)(&Pl[wave][r * 40 + ((lane >> 4) << 3)]);
    }
#pragma unroll
    for (int nt = 0; nt < 4; ++nt) {
      int d = nt * 16 + (lane & 15);
      int kk = kc * 32 + ((lane >> 4) << 3);
      bf16x8 vf = *(const bf16x8*)(&Vt[d * 168 + kk]);
      o[0][nt] = __builtin_amdgcn_mfma_f32_16x16x32_bf16(pa[0], vf, o[0][nt], 0, 0, 0);
      o[1][nt] = __builtin_amdgcn_mfma_f32_16x16x32_bf16(pa[1], vf, o[1][nt], 0, 0, 0);
    }
  }

#pragma unroll
  for (int mt = 0; mt < 2; ++mt)
#pragma unroll
    for (int nt = 0; nt < 4; ++nt)
#pragma unroll
      for (int r = 0; r < 4; ++r) {
        int row = qstart + mt * 16 + ((lane >> 4) << 2) + r;
        int d = nt * 16 + (lane & 15);
        float val = o[mt][nt][r] / lrow[mt][r];
        attn[((size_t)row * NH + head) * HD + d] = f2bf(val);
      }
}

extern "C" void kernel_launch(void* const* d_in, const int* in_sizes, int n_in,
                              void* d_out, int out_size, void* d_ws, size_t ws_size,
                              hipStream_t stream) {
  const float* x      = (const float*)d_in[0];
  const float* nscale = (const float*)d_in[1];
  const float* qkv_w  = (const float*)d_in[2];
  const float* qkv_b  = (const float*)d_in[3];
  const float* out_w  = (const float*)d_in[4];
  const float* out_b  = (const float*)d_in[5];
  const float* sinks  = (const float*)d_in[6];
  float* out = (float*)d_out;
  int n = in_sizes[0] / HIDDEN;  // 1536

  char* ws = (char*)d_ws;
  size_t off = 0;
  auto alloc = [&](size_t bytes) {
    char* p = ws + off;
    off += (bytes + 255) & ~(size_t)255;
    return p;
  };
  ushort* t_bf    = (ushort*)alloc((size_t)n * HIDDEN * 2);
  ushort* qkvw_bf = (ushort*)alloc((size_t)QKV_DIM * HIDDEN * 2);
  ushort* outw_bf = (ushort*)alloc((size_t)HIDDEN * ATT_DIM * 2);
  float*  qkv     = (float*)alloc((size_t)n * QKV_DIM * 4);
  ushort* q_bf    = (ushort*)alloc((size_t)n * NH * HD * 2);
  ushort* k_bf    = (ushort*)alloc((size_t)n * NKV * HD * 2);
  ushort* v_bf    = (ushort*)alloc((size_t)n * NKV * HD * 2);
  ushort* attn    = (ushort*)alloc((size_t)n * ATT_DIM * 2);

  cvt_f32_bf16<<<2048, 256, 0, stream>>>(qkv_w, qkvw_bf, QKV_DIM * HIDDEN / 4);
  cvt_f32_bf16<<<2048, 256, 0, stream>>>(out_w, outw_bf, HIDDEN * ATT_DIM / 4);
  rmsnorm_bf16<<<n, 256, 0, stream>>>(x, nscale, t_bf);
  // QKV: M=1536 N=5120 K=2880 -> 12 x 40 = 480 blocks
  gemm_reg<0><<<(n / 128) * (QKV_DIM / 128), 256, 0, stream>>>(
      t_bf, qkvw_bf, qkv_b, nullptr, qkv, n, QKV_DIM, HIDDEN, n / 128);
  rope_split<<<n, 256, 0, stream>>>(qkv, q_bf, k_bf, v_bf);
  attn_fused<<<dim3(n / 32, NKV), 512, 0, stream>>>(q_bf, k_bf, v_bf, sinks, attn, n);
  // out: M=1536 N=2880 K=4096 -> 12 x 23 = 276 blocks (last N-panel masked)
  gemm_reg<1><<<(n / 128) * ((HIDDEN + 127) / 128), 256, 0, stream>>>(
      attn, outw_bf, out_b, x, out, n, HIDDEN, ATT_DIM, n / 128);
}

// Round 5
// 227.342 us; speedup vs baseline: 2.1317x; 2.1317x over previous
//
#include <hip/hip_runtime.h>

typedef __attribute__((ext_vector_type(8))) short bf16x8;
typedef __attribute__((ext_vector_type(4))) float f32x4;

#define HIDDEN 2880
#define QKV_DIM 5120
#define NH 64
#define NKV 8
#define HD 64
#define ATT_DIM 4096
#define WINDOW 128
#define SM_SCALE 0.125f

__device__ __forceinline__ ushort f2bf(float f) {
  union { float f; unsigned u; } a; a.f = f;
  unsigned r = a.u + 0x7fffu + ((a.u >> 16) & 1u);
  return (ushort)(r >> 16);
}

__device__ __forceinline__ void gload_lds16(const void* g, void* l) {
  __builtin_amdgcn_global_load_lds((const __attribute__((address_space(1))) void*)g,
                                   (__attribute__((address_space(3))) void*)l, 16, 0, 0);
}

// ---------------- f32 -> bf16 convert ----------------
__global__ __launch_bounds__(256) void cvt_f32_bf16(const float* __restrict__ in,
                                                    ushort* __restrict__ out, int n4) {
  int i = blockIdx.x * blockDim.x + threadIdx.x;
  int stride = gridDim.x * blockDim.x;
  for (; i < n4; i += stride) {
    float4 v = ((const float4*)in)[i];
    ushort4 o = { f2bf(v.x), f2bf(v.y), f2bf(v.z), f2bf(v.w) };
    ((ushort4*)out)[i] = o;
  }
}

// ---------------- RMSNorm -> bf16 ----------------
__global__ __launch_bounds__(256) void rmsnorm_bf16(const float* __restrict__ x,
                                                    const float* __restrict__ scale,
                                                    ushort* __restrict__ t) {
  int row = blockIdx.x;
  int tid = threadIdx.x;
  const float4* xr = (const float4*)(x + (size_t)row * HIDDEN);
  float4 a0 = xr[tid];
  float4 a1 = xr[tid + 256];
  bool has2 = tid < 208;
  float4 a2 = has2 ? xr[tid + 512] : float4{0.f, 0.f, 0.f, 0.f};
  float ss = a0.x*a0.x + a0.y*a0.y + a0.z*a0.z + a0.w*a0.w
           + a1.x*a1.x + a1.y*a1.y + a1.z*a1.z + a1.w*a1.w
           + a2.x*a2.x + a2.y*a2.y + a2.z*a2.z + a2.w*a2.w;
  for (int m = 1; m < 64; m <<= 1) ss += __shfl_xor(ss, m, 64);
  __shared__ float red[4];
  if ((tid & 63) == 0) red[tid >> 6] = ss;
  __syncthreads();
  ss = red[0] + red[1] + red[2] + red[3];
  float r = rsqrtf(ss / (float)HIDDEN + 1e-5f);
  ushort4* tr = (ushort4*)(t + (size_t)row * HIDDEN);
  const float4* sc4 = (const float4*)scale;
  {
    float4 s = sc4[tid];
    ushort4 o = { f2bf(a0.x*r*s.x), f2bf(a0.y*r*s.y), f2bf(a0.z*r*s.z), f2bf(a0.w*r*s.w) };
    tr[tid] = o;
  }
  {
    float4 s = sc4[tid + 256];
    ushort4 o = { f2bf(a1.x*r*s.x), f2bf(a1.y*r*s.y), f2bf(a1.z*r*s.z), f2bf(a1.w*r*s.w) };
    tr[tid + 256] = o;
  }
  if (has2) {
    float4 s = sc4[tid + 512];
    ushort4 o = { f2bf(a2.x*r*s.x), f2bf(a2.y*r*s.y), f2bf(a2.z*r*s.z), f2bf(a2.w*r*s.w) };
    tr[tid + 512] = o;
  }
}

// ---------------- split-K bf16 GEMM: P[sk] = A[M,K] * B[N,K]^T over K-slice ----------------
// R1-proven m97 structure (128x128, 4 waves, single LDS buffer, 2 barriers/tile).
// Split-K (grid.y = NSK) lifts blocks/CU to 3-4 so resident blocks overlap phases (m114/m102).
__global__ __launch_bounds__(256)
void gemm_sk(const ushort* __restrict__ A, const ushort* __restrict__ B,
             float* __restrict__ P, int M, int N, int K, int NSK) {
  __shared__ __align__(16) ushort Al[128 * 64];
  __shared__ __align__(16) ushort Bl[128 * 64];
  int tid = threadIdx.x;
  int wave = tid >> 6, lane = tid & 63;
  // bijective XCD swizzle (m204) on x within each sk slice
  int nwg = gridDim.x, orig = blockIdx.x;
  int q8 = nwg >> 3, r8 = nwg & 7, xcd = orig & 7, seq = orig >> 3;
  int swz = (xcd < r8 ? xcd * (q8 + 1) : r8 * (q8 + 1) + (xcd - r8) * q8) + seq;
  int nm = M >> 7;
  int bm = swz % nm, bn = swz / nm;
  int row0 = bm * 128, col0 = bn * 128;
  int sk = blockIdx.y;
  int NT = K >> 6;
  int t0 = sk * NT / NSK, t1 = (sk + 1) * NT / NSK;
  float* Pp = P + (size_t)sk * M * N;

  int srow = wave * 32 + (lane >> 3);
  int schunk = (lane & 7) ^ (lane >> 3);
  const ushort* Ab = A + (size_t)(row0 + srow) * K + schunk * 8;
  int wr = (wave >> 1) * 64, wc = (wave & 1) * 64;
  f32x4 acc[4][4] = {};

  for (int t = t0; t < t1; ++t) {
    int k0 = t << 6;
#pragma unroll
    for (int q = 0; q < 4; ++q) {
      gload_lds16(Ab + (size_t)(q * 8) * K + k0, Al + (wave * 4 + q) * 512);
      int br = col0 + srow + q * 8;
      if (br > N - 1) br = N - 1;
      gload_lds16(B + (size_t)br * K + k0 + schunk * 8, Bl + (wave * 4 + q) * 512);
    }
    __syncthreads();
#pragma unroll
    for (int ks = 0; ks < 2; ++ks) {
      bf16x8 af[4];
#pragma unroll
      for (int mt = 0; mt < 4; ++mt) {
        int r = wr + mt * 16 + (lane & 15);
        int off = (r * 128 + (ks * 32 + ((lane >> 4) << 3)) * 2) ^ ((r & 7) << 4);
        af[mt] = *(const bf16x8*)((const char*)Al + off);
      }
#pragma unroll
      for (int nt = 0; nt < 4; ++nt) {
        int r = wc + nt * 16 + (lane & 15);
        int off = (r * 128 + (ks * 32 + ((lane >> 4) << 3)) * 2) ^ ((r & 7) << 4);
        bf16x8 bfr = *(const bf16x8*)((const char*)Bl + off);
#pragma unroll
        for (int mt = 0; mt < 4; ++mt)
          acc[mt][nt] = __builtin_amdgcn_mfma_f32_16x16x32_bf16(af[mt], bfr, acc[mt][nt], 0, 0, 0);
      }
    }
    __syncthreads();
  }
  // epilogue: C/D layout col=lane&15, row=(lane>>4)*4+r (m89-verified)
#pragma unroll
  for (int mt = 0; mt < 4; ++mt) {
#pragma unroll
    for (int nt = 0; nt < 4; ++nt) {
#pragma unroll
      for (int rr = 0; rr < 4; ++rr) {
        int row = row0 + wr + mt * 16 + ((lane >> 4) << 2) + rr;
        int col = col0 + wc + nt * 16 + (lane & 15);
        if (col < N) Pp[(size_t)row * N + col] = acc[mt][nt][rr];
      }
    }
  }
}

// ---------------- out reduce: out = x + out_b + sum_sk partials ----------------
__global__ __launch_bounds__(256)
void reduce_out(const float* __restrict__ x, const float* __restrict__ b,
                const float* __restrict__ p, int nsk, size_t stride,
                float* __restrict__ out, int n4, int N) {
  int i = blockIdx.x * blockDim.x + threadIdx.x;
  if (i >= n4) return;
  float4 v = ((const float4*)x)[i];
  int col = (i * 4) % N;
  float4 bb = *(const float4*)(b + col);
  v.x += bb.x; v.y += bb.y; v.z += bb.z; v.w += bb.w;
  for (int s = 0; s < nsk; ++s) {
    float4 pv = *(const float4*)(p + s * stride + (size_t)i * 4);
    v.x += pv.x; v.y += pv.y; v.z += pv.z; v.w += pv.w;
  }
  ((float4*)out)[i] = v;
}

// ---------------- RoPE + qkv split-K reduce + bias + split + bf16 cast ----------------
__global__ __launch_bounds__(256)
void rope_split(const float* __restrict__ p, size_t stride, const float* __restrict__ qkvb,
                ushort* __restrict__ qb, ushort* __restrict__ kb, ushort* __restrict__ vb) {
  int tok = blockIdx.x;
  int tid = threadIdx.x;
  __shared__ float cs[32], sn[32];
  if (tid < 32) {
    float d = (float)tid;
    float freq = powf(150000.0f, d / 32.0f);
    float conc = 0.1f * logf(32.0f) + 1.0f;
    float lg = logf(150000.0f);
    float low = 32.0f * logf(4096.0f / (32.0f * 6.2831853f)) / lg;
    float high = 32.0f * logf(4096.0f / 6.2831853f) / lg;
    float ramp = (d - low) / (high - low);
    float cl = fminf(fmaxf(ramp, 0.0f), 1.0f);
    float mask = 1.0f - cl;
    float inv_freq = (1.0f - mask) / (32.0f * freq) + mask / freq;
    float fr = (float)tok * inv_freq;
    cs[tid] = cosf(fr) * conc;
    sn[tid] = sinf(fr) * conc;
  }
  __syncthreads();
  const float* r0 = p + (size_t)tok * QKV_DIM;
  const float* r1 = r0 + stride;
  auto ld = [&](int c) { return r0[c] + r1[c] + qkvb[c]; };
#pragma unroll
  for (int it = 0; it < 8; ++it) {
    int pp = tid + it * 256;
    int hd = pp >> 5, d = pp & 31;
    float x1 = ld(hd * 64 + d), x2 = ld(hd * 64 + d + 32);
    float c = cs[d], s = sn[d];
    size_t o = ((size_t)tok * NH + hd) * HD + d;
    qb[o] = f2bf(x1 * c - x2 * s);
    qb[o + 32] = f2bf(x2 * c + x1 * s);
  }
  {
    int pp = tid;
    int hd = pp >> 5, d = pp & 31;
    float x1 = ld(4096 + hd * 64 + d), x2 = ld(4096 + hd * 64 + d + 32);
    float c = cs[d], s = sn[d];
    size_t o = ((size_t)tok * NKV + hd) * HD + d;
    kb[o] = f2bf(x1 * c - x2 * s);
    kb[o + 32] = f2bf(x2 * c + x1 * s);
  }
#pragma unroll
  for (int it = 0; it < 2; ++it) {
    int pp = tid + it * 256;
    vb[(size_t)tok * (NKV * HD) + pp] = f2bf(ld(4608 + pp));
  }
}

// ---------------- attention: sliding window 128 + sink ----------------
__global__ __launch_bounds__(512)
void attn_fused(const ushort* __restrict__ qb, const ushort* __restrict__ kb,
                const ushort* __restrict__ vb, const float* __restrict__ sinks,
                ushort* __restrict__ attn, int n) {
  __shared__ __align__(16) ushort Kl[160 * 64];
  __shared__ __align__(16) ushort Vt[64 * 168];
  __shared__ __align__(16) ushort Pl[8][32 * 40];
  int tid = threadIdx.x;
  int wave = tid >> 6, lane = tid & 63;
  int qstart = blockIdx.x * 32;
  int kv = blockIdx.y;
  int head = kv * 8 + wave;
  int key0 = qstart - 128;

  for (int i = 0; i < 3; ++i) {
    int rowb = i * 64 + wave * 8;
    if (rowb < 160) {
      int r = rowb + (lane >> 3);
      int gj = key0 + r; if (gj < 0) gj = 0;
      int chunk = (lane & 7) ^ (lane >> 3);
      gload_lds16(kb + ((size_t)gj * NKV + kv) * HD + chunk * 8, Kl + rowb * 64);
    }
  }
  for (int e = tid; e < 160 * 16; e += 512) {
    int j = e >> 4, d4 = (e & 15) << 2;
    int gj = key0 + j; if (gj < 0) gj = 0;
    ushort4 v = *(const ushort4*)(vb + ((size_t)gj * NKV + kv) * HD + d4);
    Vt[(d4 + 0) * 168 + j] = v.x;
    Vt[(d4 + 1) * 168 + j] = v.y;
    Vt[(d4 + 2) * 168 + j] = v.z;
    Vt[(d4 + 3) * 168 + j] = v.w;
  }
  bf16x8 qf[2][2];
#pragma unroll
  for (int mt = 0; mt < 2; ++mt)
#pragma unroll
    for (int ks = 0; ks < 2; ++ks) {
      int r = qstart + mt * 16 + (lane & 15);
      int kk = ks * 32 + ((lane >> 4) << 3);
      qf[mt][ks] = *(const bf16x8*)(qb + ((size_t)r * NH + head) * HD + kk);
    }
  __syncthreads();

  f32x4 s[2][10] = {};
#pragma unroll
  for (int nt = 0; nt < 10; ++nt) {
#pragma unroll
    for (int ks = 0; ks < 2; ++ks) {
      int r = nt * 16 + (lane & 15);
      int off = (r * 128 + (ks * 32 + ((lane >> 4) << 3)) * 2) ^ ((r & 7) << 4);
      bf16x8 kf = *(const bf16x8*)((const char*)Kl + off);
      s[0][nt] = __builtin_amdgcn_mfma_f32_16x16x32_bf16(qf[0][ks], kf, s[0][nt], 0, 0, 0);
      s[1][nt] = __builtin_amdgcn_mfma_f32_16x16x32_bf16(qf[1][ks], kf, s[1][nt], 0, 0, 0);
    }
  }

  float lrow[2][4];
  float snk = sinks[head];
#pragma unroll
  for (int mt = 0; mt < 2; ++mt) {
#pragma unroll
    for (int r = 0; r < 4; ++r) {
      int i = qstart + mt * 16 + ((lane >> 4) << 2) + r;
      float mx = -1e30f;
#pragma unroll
      for (int nt = 0; nt < 10; ++nt) {
        int j = key0 + nt * 16 + (lane & 15);
        bool ok = (j >= 0) && (j <= i) && (j > i - WINDOW);
        float val = ok ? s[mt][nt][r] * SM_SCALE : -1e30f;
        s[mt][nt][r] = val;
        mx = fmaxf(mx, val);
      }
      mx = fmaxf(mx, __shfl_xor(mx, 1, 64));
      mx = fmaxf(mx, __shfl_xor(mx, 2, 64));
      mx = fmaxf(mx, __shfl_xor(mx, 4, 64));
      mx = fmaxf(mx, __shfl_xor(mx, 8, 64));
      mx = fmaxf(mx, snk);
      float sum = 0.f;
#pragma unroll
      for (int nt = 0; nt < 10; ++nt) {
        float pv = expf(s[mt][nt][r] - mx);
        s[mt][nt][r] = pv;
        sum += pv;
      }
      sum += __shfl_xor(sum, 1, 64);
      sum += __shfl_xor(sum, 2, 64);
      sum += __shfl_xor(sum, 4, 64);
      sum += __shfl_xor(sum, 8, 64);
      sum += expf(snk - mx);
      lrow[mt][r] = sum;
    }
  }

  f32x4 o[2][4] = {};
#pragma unroll
  for (int kc = 0; kc < 5; ++kc) {
    __syncthreads();
#pragma unroll
    for (int mt = 0; mt < 2; ++mt)
#pragma unroll
      for (int t2 = 0; t2 < 2; ++t2) {
        int nt = kc * 2 + t2;
#pragma unroll
        for (int r = 0; r < 4; ++r) {
          int prow = mt * 16 + ((lane >> 4) << 2) + r;
          int pcol = t2 * 16 + (lane & 15);
          Pl[wave][prow * 40 + pcol] = f2bf(s[mt][nt][r]);
        }
      }
    __syncthreads();
    bf16x8 pa[2];
#pragma unroll
    for (int mt = 0; mt < 2; ++mt) {
      int r = mt * 16 + (lane & 15);
      pa[mt] = *(const bf16x8*)(&Pl[wave][r * 40 + ((lane >> 4) << 3)]);
    }
#pragma unroll
    for (int nt = 0; nt < 4; ++nt) {
      int d = nt * 16 + (lane & 15);
      int kk = kc * 32 + ((lane >> 4) << 3);
      bf16x8 vf = *(const bf16x8*)(&Vt[d * 168 + kk]);
      o[0][nt] = __builtin_amdgcn_mfma_f32_16x16x32_bf16(pa[0], vf, o[0][nt], 0, 0, 0);
      o[1][nt] = __builtin_amdgcn_mfma_f32_16x16x32_bf16(pa[1], vf, o[1][nt], 0, 0, 0);
    }
  }

#pragma unroll
  for (int mt = 0; mt < 2; ++mt)
#pragma unroll
    for (int nt = 0; nt < 4; ++nt)
#pragma unroll
      for (int r = 0; r < 4; ++r) {
        int row = qstart + mt * 16 + ((lane >> 4) << 2) + r;
        int d = nt * 16 + (lane & 15);
        float val = o[mt][nt][r] / lrow[mt][r];
        attn[((size_t)row * NH + head) * HD + d] = f2bf(val);
      }
}

extern "C" void kernel_launch(void* const* d_in, const int* in_sizes, int n_in,
                              void* d_out, int out_size, void* d_ws, size_t ws_size,
                              hipStream_t stream) {
  const float* x      = (const float*)d_in[0];
  const float* nscale = (const float*)d_in[1];
  const float* qkv_w  = (const float*)d_in[2];
  const float* qkv_b  = (const float*)d_in[3];
  const float* out_w  = (const float*)d_in[4];
  const float* out_b  = (const float*)d_in[5];
  const float* sinks  = (const float*)d_in[6];
  float* out = (float*)d_out;
  int n = in_sizes[0] / HIDDEN;  // 1536

  char* ws = (char*)d_ws;
  size_t off = 0;
  auto alloc = [&](size_t bytes) {
    char* p = ws + off;
    off += (bytes + 255) & ~(size_t)255;
    return p;
  };
  ushort* t_bf    = (ushort*)alloc((size_t)n * HIDDEN * 2);
  ushort* qkvw_bf = (ushort*)alloc((size_t)QKV_DIM * HIDDEN * 2);
  ushort* outw_bf = (ushort*)alloc((size_t)HIDDEN * ATT_DIM * 2);
  ushort* q_bf    = (ushort*)alloc((size_t)n * NH * HD * 2);
  ushort* k_bf    = (ushort*)alloc((size_t)n * NKV * HD * 2);
  ushort* v_bf    = (ushort*)alloc((size_t)n * NKV * HD * 2);
  ushort* attn    = (ushort*)alloc((size_t)n * ATT_DIM * 2);
  // shared partial region: qkv partials (2 x n*5120 f32) dead before out partials (3 x n*2880 f32)
  size_t qkv_ps = (size_t)n * QKV_DIM;          // elements per qkv slice
  size_t out_ps = (size_t)n * HIDDEN;           // elements per out slice
  size_t pelems = 2 * qkv_ps > 3 * out_ps ? 2 * qkv_ps : 3 * out_ps;
  float* partials = (float*)alloc(pelems * 4);

  cvt_f32_bf16<<<2048, 256, 0, stream>>>(qkv_w, qkvw_bf, QKV_DIM * HIDDEN / 4);
  cvt_f32_bf16<<<2048, 256, 0, stream>>>(out_w, outw_bf, HIDDEN * ATT_DIM / 4);
  rmsnorm_bf16<<<n, 256, 0, stream>>>(x, nscale, t_bf);
  // QKV: M=1536 N=5120 K=2880, split-K x2 -> 480x2 = 960 blocks (~3.75/CU)
  gemm_sk<<<dim3((n / 128) * (QKV_DIM / 128), 2), 256, 0, stream>>>(
      t_bf, qkvw_bf, partials, n, QKV_DIM, HIDDEN, 2);
  rope_split<<<n, 256, 0, stream>>>(partials, qkv_ps, qkv_b, q_bf, k_bf, v_bf);
  attn_fused<<<dim3(n / 32, NKV), 512, 0, stream>>>(q_bf, k_bf, v_bf, sinks, attn, n);
  // out: M=1536 N=2880 K=4096, split-K x3 -> 276x3 = 828 blocks (~3.2/CU)
  gemm_sk<<<dim3((n / 128) * ((HIDDEN + 127) / 128), 3), 256, 0, stream>>>(
      attn, outw_bf, partials, n, HIDDEN, ATT_DIM, 3);
  reduce_out<<<(n * HIDDEN / 4 + 255) / 256, 256, 0, stream>>>(
      x, out_b, partials, 3, out_ps, out, n * HIDDEN / 4, HIDDEN);
}

// Round 6
// 193.096 us; speedup vs baseline: 2.5097x; 1.1774x over previous
//
#include <hip/hip_runtime.h>

typedef __attribute__((ext_vector_type(8))) short bf16x8;
typedef __attribute__((ext_vector_type(4))) float f32x4;

#define HIDDEN 2880
#define QKV_DIM 5120
#define NH 64
#define NKV 8
#define HD 64
#define ATT_DIM 4096
#define WINDOW 128
#define SM_SCALE 0.125f

__device__ __forceinline__ ushort f2bf(float f) {
  union { float f; unsigned u; } a; a.f = f;
  unsigned r = a.u + 0x7fffu + ((a.u >> 16) & 1u);
  return (ushort)(r >> 16);
}

__device__ __forceinline__ void gload_lds16(const void* g, void* l) {
  __builtin_amdgcn_global_load_lds((const __attribute__((address_space(1))) void*)g,
                                   (__attribute__((address_space(3))) void*)l, 16, 0, 0);
}

// ---------------- f32 -> bf16 convert ----------------
__global__ __launch_bounds__(256) void cvt_f32_bf16(const float* __restrict__ in,
                                                    ushort* __restrict__ out, int n4) {
  int i = blockIdx.x * blockDim.x + threadIdx.x;
  int stride = gridDim.x * blockDim.x;
  for (; i < n4; i += stride) {
    float4 v = ((const float4*)in)[i];
    ushort4 o = { f2bf(v.x), f2bf(v.y), f2bf(v.z), f2bf(v.w) };
    ((ushort4*)out)[i] = o;
  }
}

// ---------------- RMSNorm -> bf16 ----------------
__global__ __launch_bounds__(256) void rmsnorm_bf16(const float* __restrict__ x,
                                                    const float* __restrict__ scale,
                                                    ushort* __restrict__ t) {
  int row = blockIdx.x;
  int tid = threadIdx.x;
  const float4* xr = (const float4*)(x + (size_t)row * HIDDEN);
  float4 a0 = xr[tid];
  float4 a1 = xr[tid + 256];
  bool has2 = tid < 208;
  float4 a2 = has2 ? xr[tid + 512] : float4{0.f, 0.f, 0.f, 0.f};
  float ss = a0.x*a0.x + a0.y*a0.y + a0.z*a0.z + a0.w*a0.w
           + a1.x*a1.x + a1.y*a1.y + a1.z*a1.z + a1.w*a1.w
           + a2.x*a2.x + a2.y*a2.y + a2.z*a2.z + a2.w*a2.w;
  for (int m = 1; m < 64; m <<= 1) ss += __shfl_xor(ss, m, 64);
  __shared__ float red[4];
  if ((tid & 63) == 0) red[tid >> 6] = ss;
  __syncthreads();
  ss = red[0] + red[1] + red[2] + red[3];
  float r = rsqrtf(ss / (float)HIDDEN + 1e-5f);
  ushort4* tr = (ushort4*)(t + (size_t)row * HIDDEN);
  const float4* sc4 = (const float4*)scale;
  {
    float4 s = sc4[tid];
    ushort4 o = { f2bf(a0.x*r*s.x), f2bf(a0.y*r*s.y), f2bf(a0.z*r*s.z), f2bf(a0.w*r*s.w) };
    tr[tid] = o;
  }
  {
    float4 s = sc4[tid + 256];
    ushort4 o = { f2bf(a1.x*r*s.x), f2bf(a1.y*r*s.y), f2bf(a1.z*r*s.z), f2bf(a1.w*r*s.w) };
    tr[tid + 256] = o;
  }
  if (has2) {
    float4 s = sc4[tid + 512];
    ushort4 o = { f2bf(a2.x*r*s.x), f2bf(a2.y*r*s.y), f2bf(a2.z*r*s.z), f2bf(a2.w*r*s.w) };
    tr[tid + 512] = o;
  }
}

// -------- 256x256 8-phase pipelined bf16 GEMM (split-K): P[sk] = A * B^T K-slice --------
// 8 waves (2M x 4N), BK=64, 2 K-tile LDS buffers (128 KiB). 4 phases/K-tile:
// P1 {read af(mh0)+bf0, bar, MFMA q(0,0), bar}  P2 {read bf1, stage t+2:A0,A2, ...q(0,1)}
// P3 {read af(mh1), stage t+2:B0..B3, ...q(1,1)}  P4 {stage t+2:A1,A3, ...q(1,0), vmcnt(8)}
// Stage of t+2 reuses tile t's buffer; each region staged only after the barrier ending
// its last read (A0/A2 read P1 only; all B read by P2; A1/A3 read P3). Counted vmcnt(8)
// (= t+2's 8 stage instrs in flight) keeps the pipeline 1 tile deep, never drains to 0.
template <int MASK_N>
__global__ __launch_bounds__(512)
void gemm_8p(const ushort* __restrict__ A, const ushort* __restrict__ B,
             float* __restrict__ P, int M, int N, int K, int NSK) {
  __shared__ __align__(16) ushort Al[2][256 * 64];
  __shared__ __align__(16) ushort Bl[2][256 * 64];
  const int tid = threadIdx.x;
  const int wave = tid >> 6, lane = tid & 63;
  const int l15 = lane & 15, hi = lane >> 4;

  // bijective XCD swizzle (m204) on x
  int nwg = gridDim.x, orig = blockIdx.x;
  int q8 = nwg >> 3, r8 = nwg & 7, xcd = orig & 7, seq = orig >> 3;
  int swz = (xcd < r8 ? xcd * (q8 + 1) : r8 * (q8 + 1) + (xcd - r8) * q8) + seq;
  int nm = M >> 8;
  int bm = swz % nm, bn = swz / nm;
  const int row0 = bm * 256, col0 = bn * 256;
  const int sk = blockIdx.y;
  const int NTtot = K >> 6;
  const int tt0 = sk * NTtot / NSK, tt1 = (sk + 1) * NTtot / NSK;
  float* Pp = P + (size_t)sk * M * N;

  const int wrow = (wave >> 2) * 128;
  const int wcol = (wave & 3) * 64;
  const int srow = lane >> 3;                    // 0..7
  const int schunk = (lane & 7) ^ srow;          // pre-swizzled source 16B chunk

  f32x4 acc[8][4] = {};

  auto stageA = [&](int t, int r) {
    int row = row0 + r * 64 + wave * 8 + srow;
    gload_lds16(A + (size_t)row * K + (t << 6) + schunk * 8,
                &Al[t & 1][(r * 64 + wave * 8) * 64]);
  };
  auto stageB = [&](int t, int r) {
    int brow = col0 + r * 64 + wave * 8 + srow;
    if (MASK_N) { if (brow > N - 1) brow = N - 1; }
    gload_lds16(B + (size_t)brow * K + (t << 6) + schunk * 8,
                &Bl[t & 1][(r * 64 + wave * 8) * 64]);
  };
  auto stageAll = [&](int t) {
#pragma unroll
    for (int r = 0; r < 4; ++r) { stageA(t, r); stageB(t, r); }
  };
  auto LDA = [&](bf16x8 (&dst)[4][2], int mh, const char* base) {
#pragma unroll
    for (int mt = 0; mt < 4; ++mt)
#pragma unroll
      for (int ks = 0; ks < 2; ++ks) {
        int rr = wrow + mh * 64 + mt * 16 + l15;
        int off = (rr * 128 + ks * 64 + hi * 16) ^ ((rr & 7) << 4);
        dst[mt][ks] = *(const bf16x8*)(base + off);
      }
  };
  auto LDB = [&](bf16x8 (&dst)[2][2], int nh, const char* base) {
#pragma unroll
    for (int nt = 0; nt < 2; ++nt)
#pragma unroll
      for (int ks = 0; ks < 2; ++ks) {
        int rr = wcol + nh * 32 + nt * 16 + l15;
        int off = (rr * 128 + ks * 64 + hi * 16) ^ ((rr & 7) << 4);
        dst[nt][ks] = *(const bf16x8*)(base + off);
      }
  };
  auto MMA = [&](bf16x8 (&a)[4][2], bf16x8 (&b)[2][2], int mh, int nh) {
    __builtin_amdgcn_s_setprio(1);
#pragma unroll
    for (int ks = 0; ks < 2; ++ks)
#pragma unroll
      for (int nt = 0; nt < 2; ++nt)
#pragma unroll
        for (int mt = 0; mt < 4; ++mt)
          acc[mh * 4 + mt][nh * 2 + nt] = __builtin_amdgcn_mfma_f32_16x16x32_bf16(
              a[mt][ks], b[nt][ks], acc[mh * 4 + mt][nh * 2 + nt], 0, 0, 0);
    __builtin_amdgcn_s_setprio(0);
  };

  // prologue: stage 2 tiles
  stageAll(tt0);
  bool two = (tt1 - tt0 > 1);
  if (two) {
    stageAll(tt0 + 1);
    asm volatile("s_waitcnt vmcnt(8)" ::: "memory");
  } else {
    asm volatile("s_waitcnt vmcnt(0)" ::: "memory");
  }
  __builtin_amdgcn_s_barrier();

  for (int t = tt0; t < tt1; ++t) {
    const char* Ab = (const char*)&Al[t & 1][0];
    const char* Bb = (const char*)&Bl[t & 1][0];
    bool pre = (t + 2 < tt1);
    bf16x8 afr[4][2], bf0[2][2], bf1[2][2];
    // P1
    LDA(afr, 0, Ab);
    LDB(bf0, 0, Bb);
    __builtin_amdgcn_s_barrier();
    MMA(afr, bf0, 0, 0);
    __builtin_amdgcn_s_barrier();
    // P2
    LDB(bf1, 1, Bb);
    if (pre) { stageA(t + 2, 0); stageA(t + 2, 2); }
    __builtin_amdgcn_s_barrier();
    MMA(afr, bf1, 0, 1);
    __builtin_amdgcn_s_barrier();
    // P3
    LDA(afr, 1, Ab);
    if (pre) { stageB(t + 2, 0); stageB(t + 2, 1); stageB(t + 2, 2); stageB(t + 2, 3); }
    __builtin_amdgcn_s_barrier();
    MMA(afr, bf1, 1, 1);
    __builtin_amdgcn_s_barrier();
    // P4
    if (pre) { stageA(t + 2, 1); stageA(t + 2, 3); }
    __builtin_amdgcn_s_barrier();
    MMA(afr, bf0, 1, 0);
    if (pre) asm volatile("s_waitcnt vmcnt(8)" ::: "memory");
    else     asm volatile("s_waitcnt vmcnt(0)" ::: "memory");
    __builtin_amdgcn_s_barrier();
  }

  // epilogue: C/D layout col=lane&15, row=(lane>>4)*4+r (m89-verified)
#pragma unroll
  for (int mtg = 0; mtg < 8; ++mtg) {
#pragma unroll
    for (int nt = 0; nt < 4; ++nt) {
#pragma unroll
      for (int rr = 0; rr < 4; ++rr) {
        int row = row0 + wrow + mtg * 16 + (hi << 2) + rr;
        int col = col0 + wcol + nt * 16 + l15;
        if (!MASK_N || col < N) Pp[(size_t)row * N + col] = acc[mtg][nt][rr];
      }
    }
  }
}

// ---------------- out reduce: out = x + out_b + sum_sk partials ----------------
__global__ __launch_bounds__(256)
void reduce_out(const float* __restrict__ x, const float* __restrict__ b,
                const float* __restrict__ p, int nsk, size_t stride,
                float* __restrict__ out, int n4, int N) {
  int i = blockIdx.x * blockDim.x + threadIdx.x;
  if (i >= n4) return;
  float4 v = ((const float4*)x)[i];
  int col = (i * 4) % N;
  float4 bb = *(const float4*)(b + col);
  v.x += bb.x; v.y += bb.y; v.z += bb.z; v.w += bb.w;
  for (int s = 0; s < nsk; ++s) {
    float4 pv = *(const float4*)(p + s * stride + (size_t)i * 4);
    v.x += pv.x; v.y += pv.y; v.z += pv.z; v.w += pv.w;
  }
  ((float4*)out)[i] = v;
}

// ---------------- RoPE + qkv split-K reduce + bias + split + bf16 cast ----------------
__global__ __launch_bounds__(256)
void rope_split(const float* __restrict__ p, size_t stride, const float* __restrict__ qkvb,
                ushort* __restrict__ qb, ushort* __restrict__ kb, ushort* __restrict__ vb) {
  int tok = blockIdx.x;
  int tid = threadIdx.x;
  __shared__ float cs[32], sn[32];
  if (tid < 32) {
    float d = (float)tid;
    float freq = powf(150000.0f, d / 32.0f);
    float conc = 0.1f * logf(32.0f) + 1.0f;
    float lg = logf(150000.0f);
    float low = 32.0f * logf(4096.0f / (32.0f * 6.2831853f)) / lg;
    float high = 32.0f * logf(4096.0f / 6.2831853f) / lg;
    float ramp = (d - low) / (high - low);
    float cl = fminf(fmaxf(ramp, 0.0f), 1.0f);
    float mask = 1.0f - cl;
    float inv_freq = (1.0f - mask) / (32.0f * freq) + mask / freq;
    float fr = (float)tok * inv_freq;
    cs[tid] = cosf(fr) * conc;
    sn[tid] = sinf(fr) * conc;
  }
  __syncthreads();
  const float* r0 = p + (size_t)tok * QKV_DIM;
  const float* r1 = r0 + stride;
  auto ld = [&](int c) { return r0[c] + r1[c] + qkvb[c]; };
#pragma unroll
  for (int it = 0; it < 8; ++it) {
    int pp = tid + it * 256;
    int hd = pp >> 5, d = pp & 31;
    float x1 = ld(hd * 64 + d), x2 = ld(hd * 64 + d + 32);
    float c = cs[d], s = sn[d];
    size_t o = ((size_t)tok * NH + hd) * HD + d;
    qb[o] = f2bf(x1 * c - x2 * s);
    qb[o + 32] = f2bf(x2 * c + x1 * s);
  }
  {
    int pp = tid;
    int hd = pp >> 5, d = pp & 31;
    float x1 = ld(4096 + hd * 64 + d), x2 = ld(4096 + hd * 64 + d + 32);
    float c = cs[d], s = sn[d];
    size_t o = ((size_t)tok * NKV + hd) * HD + d;
    kb[o] = f2bf(x1 * c - x2 * s);
    kb[o + 32] = f2bf(x2 * c + x1 * s);
  }
#pragma unroll
  for (int it = 0; it < 2; ++it) {
    int pp = tid + it * 256;
    vb[(size_t)tok * (NKV * HD) + pp] = f2bf(ld(4608 + pp));
  }
}

// ---------------- attention: sliding window 128 + sink ----------------
__global__ __launch_bounds__(512)
void attn_fused(const ushort* __restrict__ qb, const ushort* __restrict__ kb,
                const ushort* __restrict__ vb, const float* __restrict__ sinks,
                ushort* __restrict__ attn, int n) {
  __shared__ __align__(16) ushort Kl[160 * 64];
  __shared__ __align__(16) ushort Vt[64 * 168];
  __shared__ __align__(16) ushort Pl[8][32 * 40];
  int tid = threadIdx.x;
  int wave = tid >> 6, lane = tid & 63;
  int qstart = blockIdx.x * 32;
  int kv = blockIdx.y;
  int head = kv * 8 + wave;
  int key0 = qstart - 128;

  for (int i = 0; i < 3; ++i) {
    int rowb = i * 64 + wave * 8;
    if (rowb < 160) {
      int r = rowb + (lane >> 3);
      int gj = key0 + r; if (gj < 0) gj = 0;
      int chunk = (lane & 7) ^ (lane >> 3);
      gload_lds16(kb + ((size_t)gj * NKV + kv) * HD + chunk * 8, Kl + rowb * 64);
    }
  }
  for (int e = tid; e < 160 * 16; e += 512) {
    int j = e >> 4, d4 = (e & 15) << 2;
    int gj = key0 + j; if (gj < 0) gj = 0;
    ushort4 v = *(const ushort4*)(vb + ((size_t)gj * NKV + kv) * HD + d4);
    Vt[(d4 + 0) * 168 + j] = v.x;
    Vt[(d4 + 1) * 168 + j] = v.y;
    Vt[(d4 + 2) * 168 + j] = v.z;
    Vt[(d4 + 3) * 168 + j] = v.w;
  }
  bf16x8 qf[2][2];
#pragma unroll
  for (int mt = 0; mt < 2; ++mt)
#pragma unroll
    for (int ks = 0; ks < 2; ++ks) {
      int r = qstart + mt * 16 + (lane & 15);
      int kk = ks * 32 + ((lane >> 4) << 3);
      qf[mt][ks] = *(const bf16x8*)(qb + ((size_t)r * NH + head) * HD + kk);
    }
  __syncthreads();

  f32x4 s[2][10] = {};
#pragma unroll
  for (int nt = 0; nt < 10; ++nt) {
#pragma unroll
    for (int ks = 0; ks < 2; ++ks) {
      int r = nt * 16 + (lane & 15);
      int off = (r * 128 + (ks * 32 + ((lane >> 4) << 3)) * 2) ^ ((r & 7) << 4);
      bf16x8 kf = *(const bf16x8*)((const char*)Kl + off);
      s[0][nt] = __builtin_amdgcn_mfma_f32_16x16x32_bf16(qf[0][ks], kf, s[0][nt], 0, 0, 0);
      s[1][nt] = __builtin_amdgcn_mfma_f32_16x16x32_bf16(qf[1][ks], kf, s[1][nt], 0, 0, 0);
    }
  }

  float lrow[2][4];
  float snk = sinks[head];
#pragma unroll
  for (int mt = 0; mt < 2; ++mt) {
#pragma unroll
    for (int r = 0; r < 4; ++r) {
      int i = qstart + mt * 16 + ((lane >> 4) << 2) + r;
      float mx = -1e30f;
#pragma unroll
      for (int nt = 0; nt < 10; ++nt) {
        int j = key0 + nt * 16 + (lane & 15);
        bool ok = (j >= 0) && (j <= i) && (j > i - WINDOW);
        float val = ok ? s[mt][nt][r] * SM_SCALE : -1e30f;
        s[mt][nt][r] = val;
        mx = fmaxf(mx, val);
      }
      mx = fmaxf(mx, __shfl_xor(mx, 1, 64));
      mx = fmaxf(mx, __shfl_xor(mx, 2, 64));
      mx = fmaxf(mx, __shfl_xor(mx, 4, 64));
      mx = fmaxf(mx, __shfl_xor(mx, 8, 64));
      mx = fmaxf(mx, snk);
      float sum = 0.f;
#pragma unroll
      for (int nt = 0; nt < 10; ++nt) {
        float pv = expf(s[mt][nt][r] - mx);
        s[mt][nt][r] = pv;
        sum += pv;
      }
      sum += __shfl_xor(sum, 1, 64);
      sum += __shfl_xor(sum, 2, 64);
      sum += __shfl_xor(sum, 4, 64);
      sum += __shfl_xor(sum, 8, 64);
      sum += expf(snk - mx);
      lrow[mt][r] = sum;
    }
  }

  f32x4 o[2][4] = {};
#pragma unroll
  for (int kc = 0; kc < 5; ++kc) {
    __syncthreads();
#pragma unroll
    for (int mt = 0; mt < 2; ++mt)
#pragma unroll
      for (int t2 = 0; t2 < 2; ++t2) {
        int nt = kc * 2 + t2;
#pragma unroll
        for (int r = 0; r < 4; ++r) {
          int prow = mt * 16 + ((lane >> 4) << 2) + r;
          int pcol = t2 * 16 + (lane & 15);
          Pl[wave][prow * 40 + pcol] = f2bf(s[mt][nt][r]);
        }
      }
    __syncthreads();
    bf16x8 pa[2];
#pragma unroll
    for (int mt = 0; mt < 2; ++mt) {
      int r = mt * 16 + (lane & 15);
      pa[mt] = *(const bf16x8*)(&Pl[wave][r * 40 + ((lane >> 4) << 3)]);
    }
#pragma unroll
    for (int nt = 0; nt < 4; ++nt) {
      int d = nt * 16 + (lane & 15);
      int kk = kc * 32 + ((lane >> 4) << 3);
      bf16x8 vf = *(const bf16x8*)(&Vt[d * 168 + kk]);
      o[0][nt] = __builtin_amdgcn_mfma_f32_16x16x32_bf16(pa[0], vf, o[0][nt], 0, 0, 0);
      o[1][nt] = __builtin_amdgcn_mfma_f32_16x16x32_bf16(pa[1], vf, o[1][nt], 0, 0, 0);
    }
  }

#pragma unroll
  for (int mt = 0; mt < 2; ++mt)
#pragma unroll
    for (int nt = 0; nt < 4; ++nt)
#pragma unroll
      for (int r = 0; r < 4; ++r) {
        int row = qstart + mt * 16 + ((lane >> 4) << 2) + r;
        int d = nt * 16 + (lane & 15);
        float val = o[mt][nt][r] / lrow[mt][r];
        attn[((size_t)row * NH + head) * HD + d] = f2bf(val);
      }
}

extern "C" void kernel_launch(void* const* d_in, const int* in_sizes, int n_in,
                              void* d_out, int out_size, void* d_ws, size_t ws_size,
                              hipStream_t stream) {
  const float* x      = (const float*)d_in[0];
  const float* nscale = (const float*)d_in[1];
  const float* qkv_w  = (const float*)d_in[2];
  const float* qkv_b  = (const float*)d_in[3];
  const float* out_w  = (const float*)d_in[4];
  const float* out_b  = (const float*)d_in[5];
  const float* sinks  = (const float*)d_in[6];
  float* out = (float*)d_out;
  int n = in_sizes[0] / HIDDEN;  // 1536

  char* ws = (char*)d_ws;
  size_t off = 0;
  auto alloc = [&](size_t bytes) {
    char* p = ws + off;
    off += (bytes + 255) & ~(size_t)255;
    return p;
  };
  ushort* t_bf    = (ushort*)alloc((size_t)n * HIDDEN * 2);
  ushort* qkvw_bf = (ushort*)alloc((size_t)QKV_DIM * HIDDEN * 2);
  ushort* outw_bf = (ushort*)alloc((size_t)HIDDEN * ATT_DIM * 2);
  ushort* q_bf    = (ushort*)alloc((size_t)n * NH * HD * 2);
  ushort* k_bf    = (ushort*)alloc((size_t)n * NKV * HD * 2);
  ushort* v_bf    = (ushort*)alloc((size_t)n * NKV * HD * 2);
  ushort* attn    = (ushort*)alloc((size_t)n * ATT_DIM * 2);
  size_t qkv_ps = (size_t)n * QKV_DIM;
  size_t out_ps = (size_t)n * HIDDEN;
  size_t pelems = 2 * qkv_ps > 3 * out_ps ? 2 * qkv_ps : 3 * out_ps;
  float* partials = (float*)alloc(pelems * 4);

  cvt_f32_bf16<<<2048, 256, 0, stream>>>(qkv_w, qkvw_bf, QKV_DIM * HIDDEN / 4);
  cvt_f32_bf16<<<2048, 256, 0, stream>>>(out_w, outw_bf, HIDDEN * ATT_DIM / 4);
  rmsnorm_bf16<<<n, 256, 0, stream>>>(x, nscale, t_bf);
  // QKV: M=1536 N=5120 K=2880, 256^2 tiles -> 6x20=120 wg, split-K x2 -> 240 wg
  gemm_8p<0><<<dim3((n / 256) * (QKV_DIM / 256), 2), 512, 0, stream>>>(
      t_bf, qkvw_bf, partials, n, QKV_DIM, HIDDEN, 2);
  rope_split<<<n, 256, 0, stream>>>(partials, qkv_ps, qkv_b, q_bf, k_bf, v_bf);
  attn_fused<<<dim3(n / 32, NKV), 512, 0, stream>>>(q_bf, k_bf, v_bf, sinks, attn, n);
  // out: M=1536 N=2880 K=4096 -> 6x12=72 wg (last N-panel masked), split-K x3 -> 216 wg
  gemm_8p<1><<<dim3((n / 256) * 12, 3), 512, 0, stream>>>(
      attn, outw_bf, partials, n, HIDDEN, ATT_DIM, 3);
  reduce_out<<<(n * HIDDEN / 4 + 255) / 256, 256, 0, stream>>>(
      x, out_b, partials, 3, out_ps, out, n * HIDDEN / 4, HIDDEN);
}

// Round 7
// 180.646 us; speedup vs baseline: 2.6827x; 1.0689x over previous
//
#include <hip/hip_runtime.h>

typedef __attribute__((ext_vector_type(8))) short bf16x8;
typedef __attribute__((ext_vector_type(4))) float f32x4;

#define HIDDEN 2880
#define QKV_DIM 5120
#define NH 64
#define NKV 8
#define HD 64
#define ATT_DIM 4096
#define WINDOW 128
#define SM_SCALE 0.125f

__device__ __forceinline__ ushort f2bf(float f) {
  union { float f; unsigned u; } a; a.f = f;
  unsigned r = a.u + 0x7fffu + ((a.u >> 16) & 1u);
  return (ushort)(r >> 16);
}

__device__ __forceinline__ void gload_lds16(const void* g, void* l) {
  __builtin_amdgcn_global_load_lds((const __attribute__((address_space(1))) void*)g,
                                   (__attribute__((address_space(3))) void*)l, 16, 0, 0);
}

// ---------------- f32 -> bf16 convert ----------------
__global__ __launch_bounds__(256) void cvt_f32_bf16(const float* __restrict__ in,
                                                    ushort* __restrict__ out, int n4) {
  int i = blockIdx.x * blockDim.x + threadIdx.x;
  int stride = gridDim.x * blockDim.x;
  for (; i < n4; i += stride) {
    float4 v = ((const float4*)in)[i];
    ushort4 o = { f2bf(v.x), f2bf(v.y), f2bf(v.z), f2bf(v.w) };
    ((ushort4*)out)[i] = o;
  }
}

// ---------------- RMSNorm -> bf16 ----------------
__global__ __launch_bounds__(256) void rmsnorm_bf16(const float* __restrict__ x,
                                                    const float* __restrict__ scale,
                                                    ushort* __restrict__ t) {
  int row = blockIdx.x;
  int tid = threadIdx.x;
  const float4* xr = (const float4*)(x + (size_t)row * HIDDEN);
  float4 a0 = xr[tid];
  float4 a1 = xr[tid + 256];
  bool has2 = tid < 208;
  float4 a2 = has2 ? xr[tid + 512] : float4{0.f, 0.f, 0.f, 0.f};
  float ss = a0.x*a0.x + a0.y*a0.y + a0.z*a0.z + a0.w*a0.w
           + a1.x*a1.x + a1.y*a1.y + a1.z*a1.z + a1.w*a1.w
           + a2.x*a2.x + a2.y*a2.y + a2.z*a2.z + a2.w*a2.w;
  for (int m = 1; m < 64; m <<= 1) ss += __shfl_xor(ss, m, 64);
  __shared__ float red[4];
  if ((tid & 63) == 0) red[tid >> 6] = ss;
  __syncthreads();
  ss = red[0] + red[1] + red[2] + red[3];
  float r = rsqrtf(ss / (float)HIDDEN + 1e-5f);
  ushort4* tr = (ushort4*)(t + (size_t)row * HIDDEN);
  const float4* sc4 = (const float4*)scale;
  {
    float4 s = sc4[tid];
    ushort4 o = { f2bf(a0.x*r*s.x), f2bf(a0.y*r*s.y), f2bf(a0.z*r*s.z), f2bf(a0.w*r*s.w) };
    tr[tid] = o;
  }
  {
    float4 s = sc4[tid + 256];
    ushort4 o = { f2bf(a1.x*r*s.x), f2bf(a1.y*r*s.y), f2bf(a1.z*r*s.z), f2bf(a1.w*r*s.w) };
    tr[tid + 256] = o;
  }
  if (has2) {
    float4 s = sc4[tid + 512];
    ushort4 o = { f2bf(a2.x*r*s.x), f2bf(a2.y*r*s.y), f2bf(a2.z*r*s.z), f2bf(a2.w*r*s.w) };
    tr[tid + 512] = o;
  }
}

// -------- 256x256 8-phase pipelined bf16 GEMM (split-K): P[sk] = A * B^T K-slice --------
template <int MASK_N>
__global__ __launch_bounds__(512)
void gemm_8p(const ushort* __restrict__ A, const ushort* __restrict__ B,
             float* __restrict__ P, int M, int N, int K, int NSK) {
  __shared__ __align__(16) ushort Al[2][256 * 64];
  __shared__ __align__(16) ushort Bl[2][256 * 64];
  const int tid = threadIdx.x;
  const int wave = tid >> 6, lane = tid & 63;
  const int l15 = lane & 15, hi = lane >> 4;

  int nwg = gridDim.x, orig = blockIdx.x;
  int q8 = nwg >> 3, r8 = nwg & 7, xcd = orig & 7, seq = orig >> 3;
  int swz = (xcd < r8 ? xcd * (q8 + 1) : r8 * (q8 + 1) + (xcd - r8) * q8) + seq;
  int nm = M >> 8;
  int bm = swz % nm, bn = swz / nm;
  const int row0 = bm * 256, col0 = bn * 256;
  const int sk = blockIdx.y;
  const int NTtot = K >> 6;
  const int tt0 = sk * NTtot / NSK, tt1 = (sk + 1) * NTtot / NSK;
  float* Pp = P + (size_t)sk * M * N;

  const int wrow = (wave >> 2) * 128;
  const int wcol = (wave & 3) * 64;
  const int srow = lane >> 3;
  const int schunk = (lane & 7) ^ srow;

  f32x4 acc[8][4] = {};

  auto stageA = [&](int t, int r) {
    int row = row0 + r * 64 + wave * 8 + srow;
    gload_lds16(A + (size_t)row * K + (t << 6) + schunk * 8,
                &Al[t & 1][(r * 64 + wave * 8) * 64]);
  };
  auto stageB = [&](int t, int r) {
    int brow = col0 + r * 64 + wave * 8 + srow;
    if (MASK_N) { if (brow > N - 1) brow = N - 1; }
    gload_lds16(B + (size_t)brow * K + (t << 6) + schunk * 8,
                &Bl[t & 1][(r * 64 + wave * 8) * 64]);
  };
  auto stageAll = [&](int t) {
#pragma unroll
    for (int r = 0; r < 4; ++r) { stageA(t, r); stageB(t, r); }
  };
  auto LDA = [&](bf16x8 (&dst)[4][2], int mh, const char* base) {
#pragma unroll
    for (int mt = 0; mt < 4; ++mt)
#pragma unroll
      for (int ks = 0; ks < 2; ++ks) {
        int rr = wrow + mh * 64 + mt * 16 + l15;
        int off = (rr * 128 + ks * 64 + hi * 16) ^ ((rr & 7) << 4);
        dst[mt][ks] = *(const bf16x8*)(base + off);
      }
  };
  auto LDB = [&](bf16x8 (&dst)[2][2], int nh, const char* base) {
#pragma unroll
    for (int nt = 0; nt < 2; ++nt)
#pragma unroll
      for (int ks = 0; ks < 2; ++ks) {
        int rr = wcol + nh * 32 + nt * 16 + l15;
        int off = (rr * 128 + ks * 64 + hi * 16) ^ ((rr & 7) << 4);
        dst[nt][ks] = *(const bf16x8*)(base + off);
      }
  };
  auto MMA = [&](bf16x8 (&a)[4][2], bf16x8 (&b)[2][2], int mh, int nh) {
    __builtin_amdgcn_s_setprio(1);
#pragma unroll
    for (int ks = 0; ks < 2; ++ks)
#pragma unroll
      for (int nt = 0; nt < 2; ++nt)
#pragma unroll
        for (int mt = 0; mt < 4; ++mt)
          acc[mh * 4 + mt][nh * 2 + nt] = __builtin_amdgcn_mfma_f32_16x16x32_bf16(
              a[mt][ks], b[nt][ks], acc[mh * 4 + mt][nh * 2 + nt], 0, 0, 0);
    __builtin_amdgcn_s_setprio(0);
  };

  stageAll(tt0);
  bool two = (tt1 - tt0 > 1);
  if (two) {
    stageAll(tt0 + 1);
    asm volatile("s_waitcnt vmcnt(8)" ::: "memory");
  } else {
    asm volatile("s_waitcnt vmcnt(0)" ::: "memory");
  }
  __builtin_amdgcn_s_barrier();

  for (int t = tt0; t < tt1; ++t) {
    const char* Ab = (const char*)&Al[t & 1][0];
    const char* Bb = (const char*)&Bl[t & 1][0];
    bool pre = (t + 2 < tt1);
    bf16x8 afr[4][2], bf0[2][2], bf1[2][2];
    // P1
    LDA(afr, 0, Ab);
    LDB(bf0, 0, Bb);
    __builtin_amdgcn_s_barrier();
    MMA(afr, bf0, 0, 0);
    __builtin_amdgcn_s_barrier();
    // P2
    LDB(bf1, 1, Bb);
    if (pre) { stageA(t + 2, 0); stageA(t + 2, 2); }
    __builtin_amdgcn_s_barrier();
    MMA(afr, bf1, 0, 1);
    __builtin_amdgcn_s_barrier();
    // P3
    LDA(afr, 1, Ab);
    if (pre) { stageB(t + 2, 0); stageB(t + 2, 1); stageB(t + 2, 2); stageB(t + 2, 3); }
    __builtin_amdgcn_s_barrier();
    MMA(afr, bf1, 1, 1);
    __builtin_amdgcn_s_barrier();
    // P4
    if (pre) { stageA(t + 2, 1); stageA(t + 2, 3); }
    __builtin_amdgcn_s_barrier();
    MMA(afr, bf0, 1, 0);
    if (pre) asm volatile("s_waitcnt vmcnt(8)" ::: "memory");
    else     asm volatile("s_waitcnt vmcnt(0)" ::: "memory");
    __builtin_amdgcn_s_barrier();
  }

#pragma unroll
  for (int mtg = 0; mtg < 8; ++mtg) {
#pragma unroll
    for (int nt = 0; nt < 4; ++nt) {
#pragma unroll
      for (int rr = 0; rr < 4; ++rr) {
        int row = row0 + wrow + mtg * 16 + (hi << 2) + rr;
        int col = col0 + wcol + nt * 16 + l15;
        if (!MASK_N || col < N) Pp[(size_t)row * N + col] = acc[mtg][nt][rr];
      }
    }
  }
}

// ---------------- out reduce: out = x + out_b + sum_sk partials ----------------
__global__ __launch_bounds__(256)
void reduce_out(const float* __restrict__ x, const float* __restrict__ b,
                const float* __restrict__ p, int nsk, size_t stride,
                float* __restrict__ out, int n4, int N) {
  int i = blockIdx.x * blockDim.x + threadIdx.x;
  if (i >= n4) return;
  float4 v = ((const float4*)x)[i];
  int col = (i * 4) % N;
  float4 bb = *(const float4*)(b + col);
  v.x += bb.x; v.y += bb.y; v.z += bb.z; v.w += bb.w;
  for (int s = 0; s < nsk; ++s) {
    float4 pv = *(const float4*)(p + s * stride + (size_t)i * 4);
    v.x += pv.x; v.y += pv.y; v.z += pv.z; v.w += pv.w;
  }
  ((float4*)out)[i] = v;
}

// ---------------- RoPE + qkv split-K reduce + bias + split + bf16 cast ----------------
__global__ __launch_bounds__(256)
void rope_split(const float* __restrict__ p, size_t stride, const float* __restrict__ qkvb,
                ushort* __restrict__ qb, ushort* __restrict__ kb, ushort* __restrict__ vb) {
  int tok = blockIdx.x;
  int tid = threadIdx.x;
  __shared__ float cs[32], sn[32];
  if (tid < 32) {
    float d = (float)tid;
    float freq = powf(150000.0f, d / 32.0f);
    float conc = 0.1f * logf(32.0f) + 1.0f;
    float lg = logf(150000.0f);
    float low = 32.0f * logf(4096.0f / (32.0f * 6.2831853f)) / lg;
    float high = 32.0f * logf(4096.0f / 6.2831853f) / lg;
    float ramp = (d - low) / (high - low);
    float cl = fminf(fmaxf(ramp, 0.0f), 1.0f);
    float mask = 1.0f - cl;
    float inv_freq = (1.0f - mask) / (32.0f * freq) + mask / freq;
    float fr = (float)tok * inv_freq;
    cs[tid] = cosf(fr) * conc;
    sn[tid] = sinf(fr) * conc;
  }
  __syncthreads();
  const float* r0 = p + (size_t)tok * QKV_DIM;
  const float* r1 = r0 + stride;
  auto ld = [&](int c) { return r0[c] + r1[c] + qkvb[c]; };
#pragma unroll
  for (int it = 0; it < 8; ++it) {
    int pp = tid + it * 256;
    int hd = pp >> 5, d = pp & 31;
    float x1 = ld(hd * 64 + d), x2 = ld(hd * 64 + d + 32);
    float c = cs[d], s = sn[d];
    size_t o = ((size_t)tok * NH + hd) * HD + d;
    qb[o] = f2bf(x1 * c - x2 * s);
    qb[o + 32] = f2bf(x2 * c + x1 * s);
  }
  {
    int pp = tid;
    int hd = pp >> 5, d = pp & 31;
    float x1 = ld(4096 + hd * 64 + d), x2 = ld(4096 + hd * 64 + d + 32);
    float c = cs[d], s = sn[d];
    size_t o = ((size_t)tok * NKV + hd) * HD + d;
    kb[o] = f2bf(x1 * c - x2 * s);
    kb[o + 32] = f2bf(x2 * c + x1 * s);
  }
#pragma unroll
  for (int it = 0; it < 2; ++it) {
    int pp = tid + it * 256;
    vb[(size_t)tok * (NKV * HD) + pp] = f2bf(ld(4608 + pp));
  }
}

// ---------------- attention: sliding window 128 + sink, 16 queries/wave ----------------
// grid (n/16, NKV), 512 threads = 8 waves; wave w -> head kv*8+w, queries [qstart,qstart+16).
// Keys [qstart-128, qstart+32) staged once; S = s[10] f32x4 (40 VGPR) stays register-resident.
// Single barrier after staging; Pl is per-wave private (no PV barriers needed).
__global__ __launch_bounds__(512)
void attn_fused(const ushort* __restrict__ qb, const ushort* __restrict__ kb,
                const ushort* __restrict__ vb, const float* __restrict__ sinks,
                ushort* __restrict__ attn, int n) {
  __shared__ __align__(16) ushort Kl[160 * 64];   // [key][dim], XOR-swizzled 128B rows
  __shared__ __align__(16) ushort Vt[64 * 168];   // [dim][key], padded stride
  __shared__ __align__(16) ushort Pl[8][16 * 40]; // per-wave P chunk [16 q][40 keys-pad]
  int tid = threadIdx.x;
  int wave = tid >> 6, lane = tid & 63;
  int l15 = lane & 15, hi = lane >> 4;
  int qstart = blockIdx.x * 16;
  int kv = blockIdx.y;
  int head = kv * 8 + wave;
  int key0 = qstart - 128;

  // stage K via global_load_lds (pre-swizzled global source, linear LDS)
  for (int i = 0; i < 3; ++i) {
    int rowb = i * 64 + wave * 8;
    if (rowb < 160) {
      int r = rowb + (lane >> 3);
      int gj = key0 + r; if (gj < 0) gj = 0;
      int chunk = (lane & 7) ^ (lane >> 3);
      gload_lds16(kb + ((size_t)gj * NKV + kv) * HD + chunk * 8, Kl + rowb * 64);
    }
  }
  // stage V transposed
  for (int e = tid; e < 160 * 16; e += 512) {
    int j = e >> 4, d4 = (e & 15) << 2;
    int gj = key0 + j; if (gj < 0) gj = 0;
    ushort4 v = *(const ushort4*)(vb + ((size_t)gj * NKV + kv) * HD + d4);
    Vt[(d4 + 0) * 168 + j] = v.x;
    Vt[(d4 + 1) * 168 + j] = v.y;
    Vt[(d4 + 2) * 168 + j] = v.z;
    Vt[(d4 + 3) * 168 + j] = v.w;
  }
  // Q fragments straight from global (16 rows)
  bf16x8 qf[2];
#pragma unroll
  for (int ks = 0; ks < 2; ++ks) {
    int r = qstart + l15;
    int kk = ks * 32 + hi * 8;
    qf[ks] = *(const bf16x8*)(qb + ((size_t)r * NH + head) * HD + kk);
  }
  __syncthreads();

  // S = Q K^T (16 x 160)
  f32x4 s[10] = {};
#pragma unroll
  for (int nt = 0; nt < 10; ++nt) {
#pragma unroll
    for (int ks = 0; ks < 2; ++ks) {
      int r = nt * 16 + l15;
      int off = (r * 128 + (ks * 32 + hi * 8) * 2) ^ ((r & 7) << 4);
      bf16x8 kf = *(const bf16x8*)((const char*)Kl + off);
      s[nt] = __builtin_amdgcn_mfma_f32_16x16x32_bf16(qf[ks], kf, s[nt], 0, 0, 0);
    }
  }

  // mask + scale + softmax (single pass; sink folded into max & denominator)
  float lrow[4];
  float snk = sinks[head];
#pragma unroll
  for (int r = 0; r < 4; ++r) {
    int i = qstart + hi * 4 + r;
    float mx = -1e30f;
#pragma unroll
    for (int nt = 0; nt < 10; ++nt) {
      int j = key0 + nt * 16 + l15;
      bool ok = (j >= 0) && (j <= i) && (j > i - WINDOW);
      float val = ok ? s[nt][r] * SM_SCALE : -1e30f;
      s[nt][r] = val;
      mx = fmaxf(mx, val);
    }
    mx = fmaxf(mx, __shfl_xor(mx, 1, 64));
    mx = fmaxf(mx, __shfl_xor(mx, 2, 64));
    mx = fmaxf(mx, __shfl_xor(mx, 4, 64));
    mx = fmaxf(mx, __shfl_xor(mx, 8, 64));
    mx = fmaxf(mx, snk);
    float sum = 0.f;
#pragma unroll
    for (int nt = 0; nt < 10; ++nt) {
      float pv = __expf(s[nt][r] - mx);
      s[nt][r] = pv;
      sum += pv;
    }
    sum += __shfl_xor(sum, 1, 64);
    sum += __shfl_xor(sum, 2, 64);
    sum += __shfl_xor(sum, 4, 64);
    sum += __shfl_xor(sum, 8, 64);
    sum += __expf(snk - mx);
    lrow[r] = sum;
  }

  // PV in 5 chunks of 32 keys; P relayout through per-wave LDS (no barriers: Pl private)
  f32x4 o[4] = {};
#pragma unroll
  for (int kc = 0; kc < 5; ++kc) {
#pragma unroll
    for (int t2 = 0; t2 < 2; ++t2) {
      int nt = kc * 2 + t2;
#pragma unroll
      for (int r = 0; r < 4; ++r)
        Pl[wave][(hi * 4 + r) * 40 + t2 * 16 + l15] = f2bf(s[nt][r]);
    }
    bf16x8 pa = *(const bf16x8*)(&Pl[wave][l15 * 40 + hi * 8]);
#pragma unroll
    for (int nt = 0; nt < 4; ++nt) {
      int d = nt * 16 + l15;
      int kk = kc * 32 + hi * 8;
      bf16x8 vf = *(const bf16x8*)(&Vt[d * 168 + kk]);
      o[nt] = __builtin_amdgcn_mfma_f32_16x16x32_bf16(pa, vf, o[nt], 0, 0, 0);
    }
  }

  // epilogue: divide by denominator, write bf16 [n][64 heads][64]
#pragma unroll
  for (int nt = 0; nt < 4; ++nt)
#pragma unroll
    for (int r = 0; r < 4; ++r) {
      int row = qstart + hi * 4 + r;
      int d = nt * 16 + l15;
      float val = o[nt][r] / lrow[r];
      attn[((size_t)row * NH + head) * HD + d] = f2bf(val);
    }
}

extern "C" void kernel_launch(void* const* d_in, const int* in_sizes, int n_in,
                              void* d_out, int out_size, void* d_ws, size_t ws_size,
                              hipStream_t stream) {
  const float* x      = (const float*)d_in[0];
  const float* nscale = (const float*)d_in[1];
  const float* qkv_w  = (const float*)d_in[2];
  const float* qkv_b  = (const float*)d_in[3];
  const float* out_w  = (const float*)d_in[4];
  const float* out_b  = (const float*)d_in[5];
  const float* sinks  = (const float*)d_in[6];
  float* out = (float*)d_out;
  int n = in_sizes[0] / HIDDEN;  // 1536

  char* ws = (char*)d_ws;
  size_t off = 0;
  auto alloc = [&](size_t bytes) {
    char* p = ws + off;
    off += (bytes + 255) & ~(size_t)255;
    return p;
  };
  ushort* t_bf    = (ushort*)alloc((size_t)n * HIDDEN * 2);
  ushort* qkvw_bf = (ushort*)alloc((size_t)QKV_DIM * HIDDEN * 2);
  ushort* outw_bf = (ushort*)alloc((size_t)HIDDEN * ATT_DIM * 2);
  ushort* q_bf    = (ushort*)alloc((size_t)n * NH * HD * 2);
  ushort* k_bf    = (ushort*)alloc((size_t)n * NKV * HD * 2);
  ushort* v_bf    = (ushort*)alloc((size_t)n * NKV * HD * 2);
  ushort* attn    = (ushort*)alloc((size_t)n * ATT_DIM * 2);
  size_t qkv_ps = (size_t)n * QKV_DIM;
  size_t out_ps = (size_t)n * HIDDEN;
  size_t pelems = 2 * qkv_ps > 3 * out_ps ? 2 * qkv_ps : 3 * out_ps;
  float* partials = (float*)alloc(pelems * 4);

  cvt_f32_bf16<<<2048, 256, 0, stream>>>(qkv_w, qkvw_bf, QKV_DIM * HIDDEN / 4);
  cvt_f32_bf16<<<2048, 256, 0, stream>>>(out_w, outw_bf, HIDDEN * ATT_DIM / 4);
  rmsnorm_bf16<<<n, 256, 0, stream>>>(x, nscale, t_bf);
  // QKV: M=1536 N=5120 K=2880, 256^2 tiles -> 6x20=120 wg, split-K x2 -> 240 wg
  gemm_8p<0><<<dim3((n / 256) * (QKV_DIM / 256), 2), 512, 0, stream>>>(
      t_bf, qkvw_bf, partials, n, QKV_DIM, HIDDEN, 2);
  rope_split<<<n, 256, 0, stream>>>(partials, qkv_ps, qkv_b, q_bf, k_bf, v_bf);
  attn_fused<<<dim3(n / 16, NKV), 512, 0, stream>>>(q_bf, k_bf, v_bf, sinks, attn, n);
  // out: M=1536 N=2880 K=4096 -> 6x12=72 wg (last N-panel masked), split-K x3 -> 216 wg
  gemm_8p<1><<<dim3((n / 256) * 12, 3), 512, 0, stream>>>(
      attn, outw_bf, partials, n, HIDDEN, ATT_DIM, 3);
  reduce_out<<<(n * HIDDEN / 4 + 255) / 256, 256, 0, stream>>>(
      x, out_b, partials, 3, out_ps, out, n * HIDDEN / 4, HIDDEN);
}

// Round 8
// 178.584 us; speedup vs baseline: 2.7137x; 1.0115x over previous
//
#include <hip/hip_runtime.h>

typedef __attribute__((ext_vector_type(8))) short bf16x8;
typedef __attribute__((ext_vector_type(4))) float f32x4;

#define HIDDEN 2880
#define QKV_DIM 5120
#define NH 64
#define NKV 8
#define HD 64
#define ATT_DIM 4096
#define WINDOW 128
#define SM_SCALE 0.125f

__device__ __forceinline__ ushort f2bf(float f) {
  union { float f; unsigned u; } a; a.f = f;
  unsigned r = a.u + 0x7fffu + ((a.u >> 16) & 1u);
  return (ushort)(r >> 16);
}

__device__ __forceinline__ void gload_lds16(const void* g, void* l) {
  __builtin_amdgcn_global_load_lds((const __attribute__((address_space(1))) void*)g,
                                   (__attribute__((address_space(3))) void*)l, 16, 0, 0);
}

// ---------------- f32 -> bf16 convert ----------------
__global__ __launch_bounds__(256) void cvt_f32_bf16(const float* __restrict__ in,
                                                    ushort* __restrict__ out, int n4) {
  int i = blockIdx.x * blockDim.x + threadIdx.x;
  int stride = gridDim.x * blockDim.x;
  for (; i < n4; i += stride) {
    float4 v = ((const float4*)in)[i];
    ushort4 o = { f2bf(v.x), f2bf(v.y), f2bf(v.z), f2bf(v.w) };
    ((ushort4*)out)[i] = o;
  }
}

// ---------------- RMSNorm -> bf16 ----------------
__global__ __launch_bounds__(256) void rmsnorm_bf16(const float* __restrict__ x,
                                                    const float* __restrict__ scale,
                                                    ushort* __restrict__ t) {
  int row = blockIdx.x;
  int tid = threadIdx.x;
  const float4* xr = (const float4*)(x + (size_t)row * HIDDEN);
  float4 a0 = xr[tid];
  float4 a1 = xr[tid + 256];
  bool has2 = tid < 208;
  float4 a2 = has2 ? xr[tid + 512] : float4{0.f, 0.f, 0.f, 0.f};
  float ss = a0.x*a0.x + a0.y*a0.y + a0.z*a0.z + a0.w*a0.w
           + a1.x*a1.x + a1.y*a1.y + a1.z*a1.z + a1.w*a1.w
           + a2.x*a2.x + a2.y*a2.y + a2.z*a2.z + a2.w*a2.w;
  for (int m = 1; m < 64; m <<= 1) ss += __shfl_xor(ss, m, 64);
  __shared__ float red[4];
  if ((tid & 63) == 0) red[tid >> 6] = ss;
  __syncthreads();
  ss = red[0] + red[1] + red[2] + red[3];
  float r = rsqrtf(ss / (float)HIDDEN + 1e-5f);
  ushort4* tr = (ushort4*)(t + (size_t)row * HIDDEN);
  const float4* sc4 = (const float4*)scale;
  {
    float4 s = sc4[tid];
    ushort4 o = { f2bf(a0.x*r*s.x), f2bf(a0.y*r*s.y), f2bf(a0.z*r*s.z), f2bf(a0.w*r*s.w) };
    tr[tid] = o;
  }
  {
    float4 s = sc4[tid + 256];
    ushort4 o = { f2bf(a1.x*r*s.x), f2bf(a1.y*r*s.y), f2bf(a1.z*r*s.z), f2bf(a1.w*r*s.w) };
    tr[tid + 256] = o;
  }
  if (has2) {
    float4 s = sc4[tid + 512];
    ushort4 o = { f2bf(a2.x*r*s.x), f2bf(a2.y*r*s.y), f2bf(a2.z*r*s.z), f2bf(a2.w*r*s.w) };
    tr[tid + 512] = o;
  }
}

// -------- 128x(64*NFRAG) triple-buffered 2-phase bf16 GEMM: C = A * B^T (+bias+resid) ----
// 8 waves (2M x 4N), wave-tile 64 x 16*NFRAG, BK=64. LDS = 3 K-tile buffers -> stage(t+2)
// never touches a buffer being read (no intra-tile hazards by construction). Per K-tile:
// 2 phases {ds_read ks-half + stage burst, BAR, setprio+MFMA+setprio, BAR}; counted
// vmcnt(S) once per tile (S = one tile's stage instrs/wave), never 0 in steady state.
// Exact tiling everywhere (no masks): M=12*128, N=20*256 / 15*192.
template <int NFRAG, int EPI>
__global__ __launch_bounds__(512)
void gemm_3b(const ushort* __restrict__ A, const ushort* __restrict__ B,
             const float* __restrict__ bias, const float* __restrict__ resid,
             float* __restrict__ C, int M, int N, int K) {
  constexpr int BROWS = 64 * NFRAG;
  __shared__ __align__(16) ushort Al[3][128 * 64];
  __shared__ __align__(16) ushort Bl[3][BROWS * 64];
  const int tid = threadIdx.x;
  const int wave = tid >> 6, lane = tid & 63;
  const int l15 = lane & 15, hi = lane >> 4;

  // bijective XCD swizzle (m204); bm-fastest so same-XCD chunk shares a B panel
  int nwg = gridDim.x, orig = blockIdx.x;
  int q8 = nwg >> 3, r8 = nwg & 7, xcd = orig & 7, seq = orig >> 3;
  int swz = (xcd < r8 ? xcd * (q8 + 1) : r8 * (q8 + 1) + (xcd - r8) * q8) + seq;
  int nm = M >> 7;
  int bm = swz % nm, bn = swz / nm;
  const int row0 = bm * 128, col0 = bn * BROWS;
  const int wrow = (wave >> 2) * 64;
  const int wcol = (wave & 3) * (16 * NFRAG);
  const int srow = lane >> 3;
  const int schunk = (lane & 7) ^ srow;
  const int NT = K >> 6;

  f32x4 acc[4][NFRAG] = {};

  auto stageA = [&](int t) {
    int b = t % 3, k0 = t << 6;
#pragma unroll
    for (int r = 0; r < 2; ++r) {
      int rowb = wave * 16 + r * 8;
      gload_lds16(A + (size_t)(row0 + rowb + srow) * K + k0 + schunk * 8, &Al[b][rowb * 64]);
    }
  };
  auto stageB = [&](int t) {
    int b = t % 3, k0 = t << 6;
#pragma unroll
    for (int r = 0; r < NFRAG; ++r) {
      int rowb = wave * (8 * NFRAG) + r * 8;
      gload_lds16(B + (size_t)(col0 + rowb + srow) * K + k0 + schunk * 8, &Bl[b][rowb * 64]);
    }
  };
  auto LDA = [&](bf16x8 (&dst)[4], int ks, const char* base) {
#pragma unroll
    for (int mt = 0; mt < 4; ++mt) {
      int rr = wrow + mt * 16 + l15;
      int off = (rr * 128 + ks * 64 + hi * 16) ^ ((rr & 7) << 4);
      dst[mt] = *(const bf16x8*)(base + off);
    }
  };
  auto LDB = [&](bf16x8 (&dst)[NFRAG], int ks, const char* base) {
#pragma unroll
    for (int nt = 0; nt < NFRAG; ++nt) {
      int rr = wcol + nt * 16 + l15;
      int off = (rr * 128 + ks * 64 + hi * 16) ^ ((rr & 7) << 4);
      dst[nt] = *(const bf16x8*)(base + off);
    }
  };
  auto MMA = [&](bf16x8 (&a)[4], bf16x8 (&b)[NFRAG]) {
    __builtin_amdgcn_s_setprio(1);
#pragma unroll
    for (int nt = 0; nt < NFRAG; ++nt)
#pragma unroll
      for (int mt = 0; mt < 4; ++mt)
        acc[mt][nt] = __builtin_amdgcn_mfma_f32_16x16x32_bf16(a[mt], b[nt], acc[mt][nt], 0, 0, 0);
    __builtin_amdgcn_s_setprio(0);
  };

  // prologue: 2 tiles in flight; wait tile 0's S instrs (oldest), keep tile 1's outstanding
  stageA(0); stageB(0);
  stageA(1); stageB(1);
  if constexpr (NFRAG == 4) asm volatile("s_waitcnt vmcnt(6)" ::: "memory");
  else                      asm volatile("s_waitcnt vmcnt(5)" ::: "memory");
  __builtin_amdgcn_s_barrier();

  for (int t = 0; t < NT; ++t) {
    const char* Ab = (const char*)&Al[t % 3][0];
    const char* Bb = (const char*)&Bl[t % 3][0];
    bool pre = (t + 2 < NT);
    bf16x8 af[4], bf[NFRAG];
    // phase 1: ks=0
    LDA(af, 0, Ab);
    LDB(bf, 0, Bb);
    if (pre) stageA(t + 2);
    __builtin_amdgcn_s_barrier();
    MMA(af, bf);
    __builtin_amdgcn_s_barrier();
    // phase 2: ks=1
    LDA(af, 1, Ab);
    LDB(bf, 1, Bb);
    if (pre) stageB(t + 2);
    __builtin_amdgcn_s_barrier();
    MMA(af, bf);
    // tile boundary: force t+1's stages landed; keep t+2's S in flight
    if (pre) {
      if constexpr (NFRAG == 4) asm volatile("s_waitcnt vmcnt(6)" ::: "memory");
      else                      asm volatile("s_waitcnt vmcnt(5)" ::: "memory");
    } else {
      asm volatile("s_waitcnt vmcnt(0)" ::: "memory");
    }
    __builtin_amdgcn_s_barrier();
  }

  // epilogue: C/D layout col=lane&15, row=(lane>>4)*4+r (m89-verified); exact tiling
#pragma unroll
  for (int mt = 0; mt < 4; ++mt) {
#pragma unroll
    for (int nt = 0; nt < NFRAG; ++nt) {
#pragma unroll
      for (int rr = 0; rr < 4; ++rr) {
        int row = row0 + wrow + mt * 16 + (hi << 2) + rr;
        int col = col0 + wcol + nt * 16 + l15;
        float v = acc[mt][nt][rr];
        if (EPI == 1) v += bias[col] + resid[(size_t)row * N + col];
        C[(size_t)row * N + col] = v;
      }
    }
  }
}

// ---------------- RoPE + bias + split + bf16 cast ----------------
__global__ __launch_bounds__(256)
void rope_split(const float* __restrict__ qkv, const float* __restrict__ qkvb,
                ushort* __restrict__ qb, ushort* __restrict__ kb, ushort* __restrict__ vb) {
  int tok = blockIdx.x;
  int tid = threadIdx.x;
  __shared__ float cs[32], sn[32];
  if (tid < 32) {
    float d = (float)tid;
    float freq = powf(150000.0f, d / 32.0f);
    float conc = 0.1f * logf(32.0f) + 1.0f;
    float lg = logf(150000.0f);
    float low = 32.0f * logf(4096.0f / (32.0f * 6.2831853f)) / lg;
    float high = 32.0f * logf(4096.0f / 6.2831853f) / lg;
    float ramp = (d - low) / (high - low);
    float cl = fminf(fmaxf(ramp, 0.0f), 1.0f);
    float mask = 1.0f - cl;
    float inv_freq = (1.0f - mask) / (32.0f * freq) + mask / freq;
    float fr = (float)tok * inv_freq;
    cs[tid] = cosf(fr) * conc;
    sn[tid] = sinf(fr) * conc;
  }
  __syncthreads();
  const float* row = qkv + (size_t)tok * QKV_DIM;
  auto ld = [&](int c) { return row[c] + qkvb[c]; };
#pragma unroll
  for (int it = 0; it < 8; ++it) {
    int pp = tid + it * 256;
    int hd = pp >> 5, d = pp & 31;
    float x1 = ld(hd * 64 + d), x2 = ld(hd * 64 + d + 32);
    float c = cs[d], s = sn[d];
    size_t o = ((size_t)tok * NH + hd) * HD + d;
    qb[o] = f2bf(x1 * c - x2 * s);
    qb[o + 32] = f2bf(x2 * c + x1 * s);
  }
  {
    int pp = tid;
    int hd = pp >> 5, d = pp & 31;
    float x1 = ld(4096 + hd * 64 + d), x2 = ld(4096 + hd * 64 + d + 32);
    float c = cs[d], s = sn[d];
    size_t o = ((size_t)tok * NKV + hd) * HD + d;
    kb[o] = f2bf(x1 * c - x2 * s);
    kb[o + 32] = f2bf(x2 * c + x1 * s);
  }
#pragma unroll
  for (int it = 0; it < 2; ++it) {
    int pp = tid + it * 256;
    vb[(size_t)tok * (NKV * HD) + pp] = f2bf(ld(4608 + pp));
  }
}

// ---------------- attention: sliding window 128 + sink, 16 queries/wave ----------------
__global__ __launch_bounds__(512)
void attn_fused(const ushort* __restrict__ qb, const ushort* __restrict__ kb,
                const ushort* __restrict__ vb, const float* __restrict__ sinks,
                ushort* __restrict__ attn, int n) {
  __shared__ __align__(16) ushort Kl[160 * 64];
  __shared__ __align__(16) ushort Vt[64 * 168];
  __shared__ __align__(16) ushort Pl[8][16 * 40];
  int tid = threadIdx.x;
  int wave = tid >> 6, lane = tid & 63;
  int l15 = lane & 15, hi = lane >> 4;
  int qstart = blockIdx.x * 16;
  int kv = blockIdx.y;
  int head = kv * 8 + wave;
  int key0 = qstart - 128;

  for (int i = 0; i < 3; ++i) {
    int rowb = i * 64 + wave * 8;
    if (rowb < 160) {
      int r = rowb + (lane >> 3);
      int gj = key0 + r; if (gj < 0) gj = 0;
      int chunk = (lane & 7) ^ (lane >> 3);
      gload_lds16(kb + ((size_t)gj * NKV + kv) * HD + chunk * 8, Kl + rowb * 64);
    }
  }
  for (int e = tid; e < 160 * 16; e += 512) {
    int j = e >> 4, d4 = (e & 15) << 2;
    int gj = key0 + j; if (gj < 0) gj = 0;
    ushort4 v = *(const ushort4*)(vb + ((size_t)gj * NKV + kv) * HD + d4);
    Vt[(d4 + 0) * 168 + j] = v.x;
    Vt[(d4 + 1) * 168 + j] = v.y;
    Vt[(d4 + 2) * 168 + j] = v.z;
    Vt[(d4 + 3) * 168 + j] = v.w;
  }
  bf16x8 qf[2];
#pragma unroll
  for (int ks = 0; ks < 2; ++ks) {
    int r = qstart + l15;
    int kk = ks * 32 + hi * 8;
    qf[ks] = *(const bf16x8*)(qb + ((size_t)r * NH + head) * HD + kk);
  }
  __syncthreads();

  f32x4 s[10] = {};
#pragma unroll
  for (int nt = 0; nt < 10; ++nt) {
#pragma unroll
    for (int ks = 0; ks < 2; ++ks) {
      int r = nt * 16 + l15;
      int off = (r * 128 + (ks * 32 + hi * 8) * 2) ^ ((r & 7) << 4);
      bf16x8 kf = *(const bf16x8*)((const char*)Kl + off);
      s[nt] = __builtin_amdgcn_mfma_f32_16x16x32_bf16(qf[ks], kf, s[nt], 0, 0, 0);
    }
  }

  float lrow[4];
  float snk = sinks[head];
#pragma unroll
  for (int r = 0; r < 4; ++r) {
    int i = qstart + hi * 4 + r;
    float mx = -1e30f;
#pragma unroll
    for (int nt = 0; nt < 10; ++nt) {
      int j = key0 + nt * 16 + l15;
      bool ok = (j >= 0) && (j <= i) && (j > i - WINDOW);
      float val = ok ? s[nt][r] * SM_SCALE : -1e30f;
      s[nt][r] = val;
      mx = fmaxf(mx, val);
    }
    mx = fmaxf(mx, __shfl_xor(mx, 1, 64));
    mx = fmaxf(mx, __shfl_xor(mx, 2, 64));
    mx = fmaxf(mx, __shfl_xor(mx, 4, 64));
    mx = fmaxf(mx, __shfl_xor(mx, 8, 64));
    mx = fmaxf(mx, snk);
    float sum = 0.f;
#pragma unroll
    for (int nt = 0; nt < 10; ++nt) {
      float pv = __expf(s[nt][r] - mx);
      s[nt][r] = pv;
      sum += pv;
    }
    sum += __shfl_xor(sum, 1, 64);
    sum += __shfl_xor(sum, 2, 64);
    sum += __shfl_xor(sum, 4, 64);
    sum += __shfl_xor(sum, 8, 64);
    sum += __expf(snk - mx);
    lrow[r] = sum;
  }

  f32x4 o[4] = {};
#pragma unroll
  for (int kc = 0; kc < 5; ++kc) {
#pragma unroll
    for (int t2 = 0; t2 < 2; ++t2) {
      int nt = kc * 2 + t2;
#pragma unroll
      for (int r = 0; r < 4; ++r)
        Pl[wave][(hi * 4 + r) * 40 + t2 * 16 + l15] = f2bf(s[nt][r]);
    }
    bf16x8 pa = *(const bf16x8*)(&Pl[wave][l15 * 40 + hi * 8]);
#pragma unroll
    for (int nt = 0; nt < 4; ++nt) {
      int d = nt * 16 + l15;
      int kk = kc * 32 + hi * 8;
      bf16x8 vf = *(const bf16x8*)(&Vt[d * 168 + kk]);
      o[nt] = __builtin_amdgcn_mfma_f32_16x16x32_bf16(pa, vf, o[nt], 0, 0, 0);
    }
  }

#pragma unroll
  for (int nt = 0; nt < 4; ++nt)
#pragma unroll
    for (int r = 0; r < 4; ++r) {
      int row = qstart + hi * 4 + r;
      int d = nt * 16 + l15;
      float val = o[nt][r] / lrow[r];
      attn[((size_t)row * NH + head) * HD + d] = f2bf(val);
    }
}

extern "C" void kernel_launch(void* const* d_in, const int* in_sizes, int n_in,
                              void* d_out, int out_size, void* d_ws, size_t ws_size,
                              hipStream_t stream) {
  const float* x      = (const float*)d_in[0];
  const float* nscale = (const float*)d_in[1];
  const float* qkv_w  = (const float*)d_in[2];
  const float* qkv_b  = (const float*)d_in[3];
  const float* out_w  = (const float*)d_in[4];
  const float* out_b  = (const float*)d_in[5];
  const float* sinks  = (const float*)d_in[6];
  float* out = (float*)d_out;
  int n = in_sizes[0] / HIDDEN;  // 1536

  char* ws = (char*)d_ws;
  size_t off = 0;
  auto alloc = [&](size_t bytes) {
    char* p = ws + off;
    off += (bytes + 255) & ~(size_t)255;
    return p;
  };
  ushort* t_bf    = (ushort*)alloc((size_t)n * HIDDEN * 2);
  ushort* qkvw_bf = (ushort*)alloc((size_t)QKV_DIM * HIDDEN * 2);
  ushort* outw_bf = (ushort*)alloc((size_t)HIDDEN * ATT_DIM * 2);
  float*  qkv     = (float*)alloc((size_t)n * QKV_DIM * 4);
  ushort* q_bf    = (ushort*)alloc((size_t)n * NH * HD * 2);
  ushort* k_bf    = (ushort*)alloc((size_t)n * NKV * HD * 2);
  ushort* v_bf    = (ushort*)alloc((size_t)n * NKV * HD * 2);
  ushort* attn    = (ushort*)alloc((size_t)n * ATT_DIM * 2);

  cvt_f32_bf16<<<2048, 256, 0, stream>>>(qkv_w, qkvw_bf, QKV_DIM * HIDDEN / 4);
  cvt_f32_bf16<<<2048, 256, 0, stream>>>(out_w, outw_bf, HIDDEN * ATT_DIM / 4);
  rmsnorm_bf16<<<n, 256, 0, stream>>>(x, nscale, t_bf);
  // QKV: M=1536 N=5120 K=2880, 128x256 tiles -> 12x20 = 240 wg (exact)
  gemm_3b<4, 0><<<(n / 128) * (QKV_DIM / 256), 512, 0, stream>>>(
      t_bf, qkvw_bf, nullptr, nullptr, qkv, n, QKV_DIM, HIDDEN);
  rope_split<<<n, 256, 0, stream>>>(qkv, qkv_b, q_bf, k_bf, v_bf);
  attn_fused<<<dim3(n / 16, NKV), 512, 0, stream>>>(q_bf, k_bf, v_bf, sinks, attn, n);
  // out: M=1536 N=2880 K=4096, 128x192 tiles -> 12x15 = 180 wg (exact); +bias +residual
  gemm_3b<3, 1><<<(n / 128) * (HIDDEN / 192), 512, 0, stream>>>(
      attn, outw_bf, out_b, x, out, n, HIDDEN, ATT_DIM);
}

// Round 9
// 177.770 us; speedup vs baseline: 2.7261x; 1.0046x over previous
//
#include <hip/hip_runtime.h>

typedef __attribute__((ext_vector_type(8))) short bf16x8;
typedef __attribute__((ext_vector_type(4))) float f32x4;

#define HIDDEN 2880
#define QKV_DIM 5120
#define NH 64
#define NKV 8
#define HD 64
#define ATT_DIM 4096
#define WINDOW 128
#define SM_SCALE 0.125f

__device__ __forceinline__ ushort f2bf(float f) {
  union { float f; unsigned u; } a; a.f = f;
  unsigned r = a.u + 0x7fffu + ((a.u >> 16) & 1u);
  return (ushort)(r >> 16);
}

__device__ __forceinline__ void gload_lds16(const void* g, void* l) {
  __builtin_amdgcn_global_load_lds((const __attribute__((address_space(1))) void*)g,
                                   (__attribute__((address_space(3))) void*)l, 16, 0, 0);
}

// ---------------- f32 -> bf16 convert (both weights, one launch) ----------------
__global__ __launch_bounds__(256) void cvt2_f32_bf16(const float* __restrict__ a, ushort* __restrict__ oa, int na4,
                                                     const float* __restrict__ b, ushort* __restrict__ ob, int nb4) {
  int i = blockIdx.x * blockDim.x + threadIdx.x;
  int stride = gridDim.x * blockDim.x;
  int tot = na4 + nb4;
  for (; i < tot; i += stride) {
    const float4* src = i < na4 ? (const float4*)a + i : (const float4*)b + (i - na4);
    ushort4* dst = i < na4 ? (ushort4*)oa + i : (ushort4*)ob + (i - na4);
    float4 v = *src;
    ushort4 o = { f2bf(v.x), f2bf(v.y), f2bf(v.z), f2bf(v.w) };
    *dst = o;
  }
}

// ---------------- RMSNorm -> bf16 ----------------
__global__ __launch_bounds__(256) void rmsnorm_bf16(const float* __restrict__ x,
                                                    const float* __restrict__ scale,
                                                    ushort* __restrict__ t) {
  int row = blockIdx.x;
  int tid = threadIdx.x;
  const float4* xr = (const float4*)(x + (size_t)row * HIDDEN);
  float4 a0 = xr[tid];
  float4 a1 = xr[tid + 256];
  bool has2 = tid < 208;
  float4 a2 = has2 ? xr[tid + 512] : float4{0.f, 0.f, 0.f, 0.f};
  float ss = a0.x*a0.x + a0.y*a0.y + a0.z*a0.z + a0.w*a0.w
           + a1.x*a1.x + a1.y*a1.y + a1.z*a1.z + a1.w*a1.w
           + a2.x*a2.x + a2.y*a2.y + a2.z*a2.z + a2.w*a2.w;
  for (int m = 1; m < 64; m <<= 1) ss += __shfl_xor(ss, m, 64);
  __shared__ float red[4];
  if ((tid & 63) == 0) red[tid >> 6] = ss;
  __syncthreads();
  ss = red[0] + red[1] + red[2] + red[3];
  float r = rsqrtf(ss / (float)HIDDEN + 1e-5f);
  ushort4* tr = (ushort4*)(t + (size_t)row * HIDDEN);
  const float4* sc4 = (const float4*)scale;
  {
    float4 s = sc4[tid];
    ushort4 o = { f2bf(a0.x*r*s.x), f2bf(a0.y*r*s.y), f2bf(a0.z*r*s.z), f2bf(a0.w*r*s.w) };
    tr[tid] = o;
  }
  {
    float4 s = sc4[tid + 256];
    ushort4 o = { f2bf(a1.x*r*s.x), f2bf(a1.y*r*s.y), f2bf(a1.z*r*s.z), f2bf(a1.w*r*s.w) };
    tr[tid + 256] = o;
  }
  if (has2) {
    float4 s = sc4[tid + 512];
    ushort4 o = { f2bf(a2.x*r*s.x), f2bf(a2.y*r*s.y), f2bf(a2.z*r*s.z), f2bf(a2.w*r*s.w) };
    tr[tid + 512] = o;
  }
}

// -------- 256x256 8-phase pipelined bf16 GEMM (split-K): P[sk] = A * B^T K-slice --------
// v2: 2-K-tile unrolled body (8 phases/iter), explicit lgkmcnt(0)+sched_barrier(0) after
// each pre-MFMA barrier (m201 per-phase pattern), counted vmcnt(6). Stage placement
// unchanged from R7 (race-safe by buffer-consumption mapping).
template <int MASK_N>
__global__ __launch_bounds__(512)
void gemm_8p(const ushort* __restrict__ A, const ushort* __restrict__ B,
             float* __restrict__ P, int M, int N, int K, int NSK) {
  __shared__ __align__(16) ushort Al[2][256 * 64];
  __shared__ __align__(16) ushort Bl[2][256 * 64];
  const int tid = threadIdx.x;
  const int wave = tid >> 6, lane = tid & 63;
  const int l15 = lane & 15, hi = lane >> 4;

  int nwg = gridDim.x, orig = blockIdx.x;
  int q8 = nwg >> 3, r8 = nwg & 7, xcd = orig & 7, seq = orig >> 3;
  int swz = (xcd < r8 ? xcd * (q8 + 1) : r8 * (q8 + 1) + (xcd - r8) * q8) + seq;
  int nm = M >> 8;
  int bm = swz % nm, bn = swz / nm;
  const int row0 = bm * 256, col0 = bn * 256;
  const int sk = blockIdx.y;
  const int NTtot = K >> 6;
  const int tt0 = sk * NTtot / NSK, tt1 = (sk + 1) * NTtot / NSK;
  float* Pp = P + (size_t)sk * M * N;

  const int wrow = (wave >> 2) * 128;
  const int wcol = (wave & 3) * 64;
  const int srow = lane >> 3;
  const int schunk = (lane & 7) ^ srow;

  f32x4 acc[8][4] = {};

  auto stageA = [&](int t, int r) {
    int row = row0 + r * 64 + wave * 8 + srow;
    gload_lds16(A + (size_t)row * K + (t << 6) + schunk * 8,
                &Al[t & 1][(r * 64 + wave * 8) * 64]);
  };
  auto stageB = [&](int t, int r) {
    int brow = col0 + r * 64 + wave * 8 + srow;
    if (MASK_N) { if (brow > N - 1) brow = N - 1; }
    gload_lds16(B + (size_t)brow * K + (t << 6) + schunk * 8,
                &Bl[t & 1][(r * 64 + wave * 8) * 64]);
  };
  auto stageAll = [&](int t) {
#pragma unroll
    for (int r = 0; r < 4; ++r) { stageA(t, r); stageB(t, r); }
  };
  auto LDA = [&](bf16x8 (&dst)[4][2], int mh, const char* base) {
#pragma unroll
    for (int mt = 0; mt < 4; ++mt)
#pragma unroll
      for (int ks = 0; ks < 2; ++ks) {
        int rr = wrow + mh * 64 + mt * 16 + l15;
        int off = (rr * 128 + ks * 64 + hi * 16) ^ ((rr & 7) << 4);
        dst[mt][ks] = *(const bf16x8*)(base + off);
      }
  };
  auto LDB = [&](bf16x8 (&dst)[2][2], int nh, const char* base) {
#pragma unroll
    for (int nt = 0; nt < 2; ++nt)
#pragma unroll
      for (int ks = 0; ks < 2; ++ks) {
        int rr = wcol + nh * 32 + nt * 16 + l15;
        int off = (rr * 128 + ks * 64 + hi * 16) ^ ((rr & 7) << 4);
        dst[nt][ks] = *(const bf16x8*)(base + off);
      }
  };
  auto MMA = [&](bf16x8 (&a)[4][2], bf16x8 (&b)[2][2], int mh, int nh) {
    __builtin_amdgcn_s_setprio(1);
#pragma unroll
    for (int ks = 0; ks < 2; ++ks)
#pragma unroll
      for (int nt = 0; nt < 2; ++nt)
#pragma unroll
        for (int mt = 0; mt < 4; ++mt)
          acc[mh * 4 + mt][nh * 2 + nt] = __builtin_amdgcn_mfma_f32_16x16x32_bf16(
              a[mt][ks], b[nt][ks], acc[mh * 4 + mt][nh * 2 + nt], 0, 0, 0);
    __builtin_amdgcn_s_setprio(0);
  };

  auto do_tile = [&](int t) {
    const char* Ab = (const char*)&Al[t & 1][0];
    const char* Bb = (const char*)&Bl[t & 1][0];
    bool pre = (t + 2 < tt1);
    bf16x8 afr[4][2], bf0[2][2], bf1[2][2];
    // P1
    LDA(afr, 0, Ab);
    LDB(bf0, 0, Bb);
    __builtin_amdgcn_s_barrier();
    asm volatile("s_waitcnt lgkmcnt(0)" ::: "memory");
    __builtin_amdgcn_sched_barrier(0);
    MMA(afr, bf0, 0, 0);
    __builtin_amdgcn_s_barrier();
    // P2
    LDB(bf1, 1, Bb);
    if (pre) { stageA(t + 2, 0); stageA(t + 2, 2); }
    __builtin_amdgcn_s_barrier();
    asm volatile("s_waitcnt lgkmcnt(0)" ::: "memory");
    __builtin_amdgcn_sched_barrier(0);
    MMA(afr, bf1, 0, 1);
    __builtin_amdgcn_s_barrier();
    // P3
    LDA(afr, 1, Ab);
    if (pre) { stageB(t + 2, 0); stageB(t + 2, 1); stageB(t + 2, 2); stageB(t + 2, 3); }
    __builtin_amdgcn_s_barrier();
    asm volatile("s_waitcnt lgkmcnt(0)" ::: "memory");
    __builtin_amdgcn_sched_barrier(0);
    MMA(afr, bf1, 1, 1);
    __builtin_amdgcn_s_barrier();
    // P4
    if (pre) { stageA(t + 2, 1); stageA(t + 2, 3); }
    __builtin_amdgcn_s_barrier();
    __builtin_amdgcn_sched_barrier(0);
    MMA(afr, bf0, 1, 0);
    if (pre) asm volatile("s_waitcnt vmcnt(6)" ::: "memory");
    else     asm volatile("s_waitcnt vmcnt(0)" ::: "memory");
    __builtin_amdgcn_s_barrier();
  };

  // prologue: 2 tiles staged; wait tile tt0's 8 loads (oldest), keep tile tt0+1's in flight
  stageAll(tt0);
  bool two = (tt1 - tt0 > 1);
  if (two) {
    stageAll(tt0 + 1);
    asm volatile("s_waitcnt vmcnt(8)" ::: "memory");
  } else {
    asm volatile("s_waitcnt vmcnt(0)" ::: "memory");
  }
  __builtin_amdgcn_s_barrier();

  int t = tt0;
  for (; t + 1 < tt1; t += 2) { do_tile(t); do_tile(t + 1); }
  if (t < tt1) do_tile(t);

  // epilogue: C/D layout col=lane&15, row=(lane>>4)*4+r (m89-verified)
#pragma unroll
  for (int mtg = 0; mtg < 8; ++mtg) {
#pragma unroll
    for (int nt = 0; nt < 4; ++nt) {
#pragma unroll
      for (int rr = 0; rr < 4; ++rr) {
        int row = row0 + wrow + mtg * 16 + (hi << 2) + rr;
        int col = col0 + wcol + nt * 16 + l15;
        if (!MASK_N || col < N) Pp[(size_t)row * N + col] = acc[mtg][nt][rr];
      }
    }
  }
}

// ---------------- out reduce: out = x + out_b + sum_sk partials ----------------
__global__ __launch_bounds__(256)
void reduce_out(const float* __restrict__ x, const float* __restrict__ b,
                const float* __restrict__ p, int nsk, size_t stride,
                float* __restrict__ out, int n4, int N) {
  int i = blockIdx.x * blockDim.x + threadIdx.x;
  if (i >= n4) return;
  float4 v = ((const float4*)x)[i];
  int col = (i * 4) % N;
  float4 bb = *(const float4*)(b + col);
  v.x += bb.x; v.y += bb.y; v.z += bb.z; v.w += bb.w;
  for (int s = 0; s < nsk; ++s) {
    float4 pv = *(const float4*)(p + s * stride + (size_t)i * 4);
    v.x += pv.x; v.y += pv.y; v.z += pv.z; v.w += pv.w;
  }
  ((float4*)out)[i] = v;
}

// ---------------- RoPE + qkv split-K reduce + bias + split + bf16 cast ----------------
__global__ __launch_bounds__(256)
void rope_split(const float* __restrict__ p, size_t stride, const float* __restrict__ qkvb,
                ushort* __restrict__ qb, ushort* __restrict__ kb, ushort* __restrict__ vb) {
  int tok = blockIdx.x;
  int tid = threadIdx.x;
  __shared__ float cs[32], sn[32];
  if (tid < 32) {
    float d = (float)tid;
    float freq = powf(150000.0f, d / 32.0f);
    float conc = 0.1f * logf(32.0f) + 1.0f;
    float lg = logf(150000.0f);
    float low = 32.0f * logf(4096.0f / (32.0f * 6.2831853f)) / lg;
    float high = 32.0f * logf(4096.0f / 6.2831853f) / lg;
    float ramp = (d - low) / (high - low);
    float cl = fminf(fmaxf(ramp, 0.0f), 1.0f);
    float mask = 1.0f - cl;
    float inv_freq = (1.0f - mask) / (32.0f * freq) + mask / freq;
    float fr = (float)tok * inv_freq;
    cs[tid] = cosf(fr) * conc;
    sn[tid] = sinf(fr) * conc;
  }
  __syncthreads();
  const float* r0 = p + (size_t)tok * QKV_DIM;
  const float* r1 = r0 + stride;
  auto ld = [&](int c) { return r0[c] + r1[c] + qkvb[c]; };
#pragma unroll
  for (int it = 0; it < 8; ++it) {
    int pp = tid + it * 256;
    int hd = pp >> 5, d = pp & 31;
    float x1 = ld(hd * 64 + d), x2 = ld(hd * 64 + d + 32);
    float c = cs[d], s = sn[d];
    size_t o = ((size_t)tok * NH + hd) * HD + d;
    qb[o] = f2bf(x1 * c - x2 * s);
    qb[o + 32] = f2bf(x2 * c + x1 * s);
  }
  {
    int pp = tid;
    int hd = pp >> 5, d = pp & 31;
    float x1 = ld(4096 + hd * 64 + d), x2 = ld(4096 + hd * 64 + d + 32);
    float c = cs[d], s = sn[d];
    size_t o = ((size_t)tok * NKV + hd) * HD + d;
    kb[o] = f2bf(x1 * c - x2 * s);
    kb[o + 32] = f2bf(x2 * c + x1 * s);
  }
#pragma unroll
  for (int it = 0; it < 2; ++it) {
    int pp = tid + it * 256;
    vb[(size_t)tok * (NKV * HD) + pp] = f2bf(ld(4608 + pp));
  }
}

// ---------------- attention: sliding window 128 + sink, 16 queries/wave ----------------
__global__ __launch_bounds__(512)
void attn_fused(const ushort* __restrict__ qb, const ushort* __restrict__ kb,
                const ushort* __restrict__ vb, const float* __restrict__ sinks,
                ushort* __restrict__ attn, int n) {
  __shared__ __align__(16) ushort Kl[160 * 64];
  __shared__ __align__(16) ushort Vt[64 * 168];
  __shared__ __align__(16) ushort Pl[8][16 * 40];
  int tid = threadIdx.x;
  int wave = tid >> 6, lane = tid & 63;
  int l15 = lane & 15, hi = lane >> 4;
  int qstart = blockIdx.x * 16;
  int kv = blockIdx.y;
  int head = kv * 8 + wave;
  int key0 = qstart - 128;

  for (int i = 0; i < 3; ++i) {
    int rowb = i * 64 + wave * 8;
    if (rowb < 160) {
      int r = rowb + (lane >> 3);
      int gj = key0 + r; if (gj < 0) gj = 0;
      int chunk = (lane & 7) ^ (lane >> 3);
      gload_lds16(kb + ((size_t)gj * NKV + kv) * HD + chunk * 8, Kl + rowb * 64);
    }
  }
  for (int e = tid; e < 160 * 16; e += 512) {
    int j = e >> 4, d4 = (e & 15) << 2;
    int gj = key0 + j; if (gj < 0) gj = 0;
    ushort4 v = *(const ushort4*)(vb + ((size_t)gj * NKV + kv) * HD + d4);
    Vt[(d4 + 0) * 168 + j] = v.x;
    Vt[(d4 + 1) * 168 + j] = v.y;
    Vt[(d4 + 2) * 168 + j] = v.z;
    Vt[(d4 + 3) * 168 + j] = v.w;
  }
  bf16x8 qf[2];
#pragma unroll
  for (int ks = 0; ks < 2; ++ks) {
    int r = qstart + l15;
    int kk = ks * 32 + hi * 8;
    qf[ks] = *(const bf16x8*)(qb + ((size_t)r * NH + head) * HD + kk);
  }
  __syncthreads();

  f32x4 s[10] = {};
#pragma unroll
  for (int nt = 0; nt < 10; ++nt) {
#pragma unroll
    for (int ks = 0; ks < 2; ++ks) {
      int r = nt * 16 + l15;
      int off = (r * 128 + (ks * 32 + hi * 8) * 2) ^ ((r & 7) << 4);
      bf16x8 kf = *(const bf16x8*)((const char*)Kl + off);
      s[nt] = __builtin_amdgcn_mfma_f32_16x16x32_bf16(qf[ks], kf, s[nt], 0, 0, 0);
    }
  }

  float lrow[4];
  float snk = sinks[head];
#pragma unroll
  for (int r = 0; r < 4; ++r) {
    int i = qstart + hi * 4 + r;
    float mx = -1e30f;
#pragma unroll
    for (int nt = 0; nt < 10; ++nt) {
      int j = key0 + nt * 16 + l15;
      bool ok = (j >= 0) && (j <= i) && (j > i - WINDOW);
      float val = ok ? s[nt][r] * SM_SCALE : -1e30f;
      s[nt][r] = val;
      mx = fmaxf(mx, val);
    }
    mx = fmaxf(mx, __shfl_xor(mx, 1, 64));
    mx = fmaxf(mx, __shfl_xor(mx, 2, 64));
    mx = fmaxf(mx, __shfl_xor(mx, 4, 64));
    mx = fmaxf(mx, __shfl_xor(mx, 8, 64));
    mx = fmaxf(mx, snk);
    float sum = 0.f;
#pragma unroll
    for (int nt = 0; nt < 10; ++nt) {
      float pv = __expf(s[nt][r] - mx);
      s[nt][r] = pv;
      sum += pv;
    }
    sum += __shfl_xor(sum, 1, 64);
    sum += __shfl_xor(sum, 2, 64);
    sum += __shfl_xor(sum, 4, 64);
    sum += __shfl_xor(sum, 8, 64);
    sum += __expf(snk - mx);
    lrow[r] = sum;
  }

  f32x4 o[4] = {};
#pragma unroll
  for (int kc = 0; kc < 5; ++kc) {
#pragma unroll
    for (int t2 = 0; t2 < 2; ++t2) {
      int nt = kc * 2 + t2;
#pragma unroll
      for (int r = 0; r < 4; ++r)
        Pl[wave][(hi * 4 + r) * 40 + t2 * 16 + l15] = f2bf(s[nt][r]);
    }
    bf16x8 pa = *(const bf16x8*)(&Pl[wave][l15 * 40 + hi * 8]);
#pragma unroll
    for (int nt = 0; nt < 4; ++nt) {
      int d = nt * 16 + l15;
      int kk = kc * 32 + hi * 8;
      bf16x8 vf = *(const bf16x8*)(&Vt[d * 168 + kk]);
      o[nt] = __builtin_amdgcn_mfma_f32_16x16x32_bf16(pa, vf, o[nt], 0, 0, 0);
    }
  }

#pragma unroll
  for (int nt = 0; nt < 4; ++nt)
#pragma unroll
    for (int r = 0; r < 4; ++r) {
      int row = qstart + hi * 4 + r;
      int d = nt * 16 + l15;
      float val = o[nt][r] / lrow[r];
      attn[((size_t)row * NH + head) * HD + d] = f2bf(val);
    }
}

extern "C" void kernel_launch(void* const* d_in, const int* in_sizes, int n_in,
                              void* d_out, int out_size, void* d_ws, size_t ws_size,
                              hipStream_t stream) {
  const float* x      = (const float*)d_in[0];
  const float* nscale = (const float*)d_in[1];
  const float* qkv_w  = (const float*)d_in[2];
  const float* qkv_b  = (const float*)d_in[3];
  const float* out_w  = (const float*)d_in[4];
  const float* out_b  = (const float*)d_in[5];
  const float* sinks  = (const float*)d_in[6];
  float* out = (float*)d_out;
  int n = in_sizes[0] / HIDDEN;  // 1536

  char* ws = (char*)d_ws;
  size_t off = 0;
  auto alloc = [&](size_t bytes) {
    char* p = ws + off;
    off += (bytes + 255) & ~(size_t)255;
    return p;
  };
  ushort* t_bf    = (ushort*)alloc((size_t)n * HIDDEN * 2);
  ushort* qkvw_bf = (ushort*)alloc((size_t)QKV_DIM * HIDDEN * 2);
  ushort* outw_bf = (ushort*)alloc((size_t)HIDDEN * ATT_DIM * 2);
  ushort* q_bf    = (ushort*)alloc((size_t)n * NH * HD * 2);
  ushort* k_bf    = (ushort*)alloc((size_t)n * NKV * HD * 2);
  ushort* v_bf    = (ushort*)alloc((size_t)n * NKV * HD * 2);
  ushort* attn    = (ushort*)alloc((size_t)n * ATT_DIM * 2);
  size_t qkv_ps = (size_t)n * QKV_DIM;
  size_t out_ps = (size_t)n * HIDDEN;
  size_t pelems = 2 * qkv_ps > 3 * out_ps ? 2 * qkv_ps : 3 * out_ps;
  float* partials = (float*)alloc(pelems * 4);

  cvt2_f32_bf16<<<2048, 256, 0, stream>>>(qkv_w, qkvw_bf, QKV_DIM * HIDDEN / 4,
                                          out_w, outw_bf, HIDDEN * ATT_DIM / 4);
  rmsnorm_bf16<<<n, 256, 0, stream>>>(x, nscale, t_bf);
  // QKV: M=1536 N=5120 K=2880, 256^2 tiles -> 6x20=120 wg, split-K x2 -> 240 wg
  gemm_8p<0><<<dim3((n / 256) * (QKV_DIM / 256), 2), 512, 0, stream>>>(
      t_bf, qkvw_bf, partials, n, QKV_DIM, HIDDEN, 2);
  rope_split<<<n, 256, 0, stream>>>(partials, qkv_ps, qkv_b, q_bf, k_bf, v_bf);
  attn_fused<<<dim3(n / 16, NKV), 512, 0, stream>>>(q_bf, k_bf, v_bf, sinks, attn, n);
  // out: M=1536 N=2880 K=4096 -> 6x12=72 wg (last N-panel masked), split-K x3 -> 216 wg
  gemm_8p<1><<<dim3((n / 256) * 12, 3), 512, 0, stream>>>(
      attn, outw_bf, partials, n, HIDDEN, ATT_DIM, 3);
  reduce_out<<<(n * HIDDEN / 4 + 255) / 256, 256, 0, stream>>>(
      x, out_b, partials, 3, out_ps, out, n * HIDDEN / 4, HIDDEN);
}